// Round 12
// baseline (535.685 us; speedup 1.0000x reference)
//
#include <hip/hip_runtime.h>
#include <hip/hip_bf16.h>
#include <stdint.h>

// ---------------- types / helpers ----------------
typedef __attribute__((ext_vector_type(8))) short bf16x8;
typedef __attribute__((ext_vector_type(8))) _Float16 f16x8;
typedef __attribute__((ext_vector_type(4))) _Float16 f16x4;
typedef __attribute__((ext_vector_type(4))) float f32x4;

__device__ __forceinline__ short f2bf(float f) {
  __hip_bfloat16 h = __float2bfloat16(f);
  union { __hip_bfloat16 h; short s; } u; u.h = h; return u.s;
}

__device__ __forceinline__ unsigned pk2(float a, float b) {
  union { _Float16 h; unsigned short s; } ua, ub;
  ua.h = (_Float16)a; ub.h = (_Float16)b;
  return (unsigned)ua.s | ((unsigned)ub.s << 16);
}

// async global->LDS, 16B per lane. LDS dest must be wave-uniform base + lane*16.
__device__ __forceinline__ void gld16(const void* g, void* l) {
  __builtin_amdgcn_global_load_lds((const __attribute__((address_space(1))) void*)g,
                                   (__attribute__((address_space(3))) void*)l, 16, 0, 0);
}

__device__ __forceinline__ float wave_sum64(float v) {
  #pragma unroll
  for (int off = 1; off < 64; off <<= 1) v += __shfl_xor(v, off);
  return v;
}
__device__ __forceinline__ double wave_sum64d(double v) {
  #pragma unroll
  for (int off = 1; off < 64; off <<= 1) v += __shfl_xor(v, off);
  return v;
}

// ---------------- LN kernels ----------------
// LN1: emits split-f16 (hi, lo*2048) directly for the DMA GEMM.
__global__ __launch_bounds__(256) void ln_split(const float* __restrict__ x,
    const float* __restrict__ g, const float* __restrict__ b,
    _Float16* __restrict__ xh, _Float16* __restrict__ xl) {
  int t = blockIdx.x, tid = threadIdx.x;
  const float4 v = ((const float4*)(x + (size_t)t * 1024))[tid];
  float s = v.x + v.y + v.z + v.w;
  float s2 = v.x*v.x + v.y*v.y + v.z*v.z + v.w*v.w;
  s = wave_sum64(s); s2 = wave_sum64(s2);
  __shared__ float pa[4], pb[4];
  int wid = tid >> 6, lane = tid & 63;
  if (lane == 0) { pa[wid] = s; pb[wid] = s2; }
  __syncthreads();
  float S = pa[0]+pa[1]+pa[2]+pa[3], S2 = pb[0]+pb[1]+pb[2]+pb[3];
  float mu = S * (1.f/1024.f);
  float var = S2 * (1.f/1024.f) - mu*mu;
  float rs = rsqrtf(var + 1e-5f);
  const float4 gv = ((const float4*)g)[tid];
  const float4 bv = ((const float4*)b)[tid];
  float4 o;
  o.x = (v.x-mu)*rs*gv.x + bv.x; o.y = (v.y-mu)*rs*gv.y + bv.y;
  o.z = (v.z-mu)*rs*gv.z + bv.z; o.w = (v.w-mu)*rs*gv.w + bv.w;
  f16x4 hv, lv;
  hv.x = (_Float16)o.x; lv.x = (_Float16)((o.x - (float)hv.x)*2048.f);
  hv.y = (_Float16)o.y; lv.y = (_Float16)((o.y - (float)hv.y)*2048.f);
  hv.z = (_Float16)o.z; lv.z = (_Float16)((o.z - (float)hv.z)*2048.f);
  hv.w = (_Float16)o.w; lv.w = (_Float16)((o.w - (float)hv.w)*2048.f);
  *(f16x4*)&xh[(size_t)t*1024 + tid*4] = hv;
  *(f16x4*)&xl[(size_t)t*1024 + tid*4] = lv;
}

// ---------------- weight transpose + fp16 hi/lo split ----------------
__global__ void t_w_f16(const float* __restrict__ src, int srcN,
                        _Float16* __restrict__ dh, _Float16* __restrict__ dl, int dstRow0) {
  __shared__ float tile[32][33];
  int kt = blockIdx.x, nt = blockIdx.y;
  int tx = threadIdx.x, ty = threadIdx.y;
  #pragma unroll
  for (int i = 0; i < 4; i++)
    tile[ty + 8*i][tx] = src[(size_t)(kt*32 + ty + 8*i)*srcN + nt*32 + tx];
  __syncthreads();
  #pragma unroll
  for (int i = 0; i < 4; i++) {
    float v = tile[tx][ty + 8*i];
    _Float16 h = (_Float16)v;
    _Float16 l = (_Float16)((v - (float)h) * 2048.0f);
    size_t o = (size_t)(dstRow0 + nt*32 + ty + 8*i)*1024 + kt*32 + tx;
    dh[o] = h; dl[o] = l;
  }
}

// ---------------- split-fp16 DMA MFMA GEMM (64x128, BK=32, dbuf, counted-vmcnt) ----------------
// r11 occupancy analysis: r8's 64x128 config was 68 VGPR + 64 AGPR = 132 combined --
// 4 regs over the 128 bracket (waves/SIMD steps at 64/128/256, m69) -> pinned at
// 2 waves/SIMD, same as the 128x128 tile (232 regs). launch_bounds(256,4) forces
// combined <=128 (VGPR <=64) -> 4 waves/SIMD; LDS 48KB -> 3 blocks/CU = 12 waves,
// 3 mutually-async blocks to cover the barrier/vmcnt idle (m114 mechanism).
// T4 schedule: counted vmcnt(6), never 0 mid-loop. Swizzle cp = c ^ ((row>>1)&3).
template<int MODE>
__global__ __launch_bounds__(256, 4) void gemm_dma(
    const _Float16* __restrict__ Agh, const _Float16* __restrict__ Agl,
    const _Float16* __restrict__ BTh, const _Float16* __restrict__ BTl,
    const float* __restrict__ b0, const float* __restrict__ b1, const float* __restrict__ b2,
    const float* __restrict__ resid,
    float* __restrict__ out0, float* __restrict__ out1, float* __restrict__ out2) {
  int m0 = blockIdx.x * 64;
  int y = blockIdx.y;
  int n0 = y * 128;
  float* dst; const float* biasp; int dcol0, ld;
  if (MODE == 0) {
    if (y < 8)      { dst = out0; biasp = b0 + y*128; dcol0 = y*128; ld = 1024; }
    else if (y == 8){ dst = out1; biasp = b1; dcol0 = 0; ld = 128; }
    else            { dst = out2; biasp = b2; dcol0 = 0; ld = 128; }
  } else            { dst = out0; biasp = b0 + y*128; dcol0 = y*128; ld = 1024; }

  __shared__ _Float16 AhS[2][2048];   // [64][32] swizzled
  __shared__ _Float16 AlS[2][2048];
  __shared__ _Float16 BhS[2][4096];   // [128][32] swizzled
  __shared__ _Float16 BlS[2][4096];
  int tid = threadIdx.x;
  int lane = tid & 63, w = tid >> 6;
  int wm = (w & 1) * 32, wn = (w >> 1) * 64;
  int l15 = lane & 15, quad = lane >> 4;

  // Staging geometry (fixed across K). A: 1 chunk/thread; B: 2 chunks/thread.
  int Pa = tid;
  int cA = (Pa & 3) ^ ((Pa >> 3) & 3);
  size_t gA = (size_t)(m0 + (Pa >> 2)) * 1024 + cA * 8;
  int Pb0 = tid, Pb1 = tid + 256;
  int cB0 = (Pb0 & 3) ^ ((Pb0 >> 3) & 3);
  int cB1 = (Pb1 & 3) ^ ((Pb1 >> 3) & 3);
  size_t gB0 = (size_t)(n0 + (Pb0 >> 2)) * 1024 + cB0 * 8;
  size_t gB1 = (size_t)(n0 + (Pb1 >> 2)) * 1024 + cB1 * 8;

  f32x4 accM[2][4] = {};
  f32x4 accC[2][4] = {};

  // prologue: stage K-tile 0 into buffer 0 (6 loads/thread)
  gld16(Agh + gA, &AhS[0][Pa*8]);
  gld16(Agl + gA, &AlS[0][Pa*8]);
  gld16(BTh + gB0, &BhS[0][Pb0*8]);
  gld16(BTh + gB1, &BhS[0][Pb1*8]);
  gld16(BTl + gB0, &BlS[0][Pb0*8]);
  gld16(BTl + gB1, &BlS[0][Pb1*8]);

  int cur = 0;
  for (int it = 0; it < 32; ++it) {
    if (it < 31) {
      int kb = (it + 1) * 32;
      int nb = cur ^ 1;
      gld16(Agh + gA + kb, &AhS[nb][Pa*8]);
      gld16(Agl + gA + kb, &AlS[nb][Pa*8]);
      gld16(BTh + gB0 + kb, &BhS[nb][Pb0*8]);
      gld16(BTh + gB1 + kb, &BhS[nb][Pb1*8]);
      gld16(BTl + gB0 + kb, &BlS[nb][Pb0*8]);
      gld16(BTl + gB1 + kb, &BlS[nb][Pb1*8]);
      asm volatile("s_waitcnt vmcnt(6)" ::: "memory");   // loads(it) done; loads(it+1) fly
    } else {
      asm volatile("s_waitcnt vmcnt(0)" ::: "memory");
    }
    __builtin_amdgcn_s_barrier();
    __builtin_amdgcn_sched_barrier(0);
    __builtin_amdgcn_s_setprio(1);
    f16x8 bh[4], bl[4];
    #pragma unroll
    for (int nt = 0; nt < 4; nt++) {
      int row = wn + nt*16 + l15;
      int pc = quad ^ ((row >> 1) & 3);
      bh[nt] = *(const f16x8*)&BhS[cur][row*32 + pc*8];
      bl[nt] = *(const f16x8*)&BlS[cur][row*32 + pc*8];
    }
    #pragma unroll
    for (int mt = 0; mt < 2; mt++) {
      int row = wm + mt*16 + l15;
      int pc = quad ^ ((row >> 1) & 3);
      f16x8 ah = *(const f16x8*)&AhS[cur][row*32 + pc*8];
      f16x8 al = *(const f16x8*)&AlS[cur][row*32 + pc*8];
      #pragma unroll
      for (int nt = 0; nt < 4; nt++) {
        accM[mt][nt] = __builtin_amdgcn_mfma_f32_16x16x32_f16(ah, bh[nt], accM[mt][nt], 0, 0, 0);
        accC[mt][nt] = __builtin_amdgcn_mfma_f32_16x16x32_f16(ah, bl[nt], accC[mt][nt], 0, 0, 0);
        accC[mt][nt] = __builtin_amdgcn_mfma_f32_16x16x32_f16(al, bh[nt], accC[mt][nt], 0, 0, 0);
      }
    }
    __builtin_amdgcn_s_setprio(0);
    asm volatile("s_waitcnt lgkmcnt(0)" ::: "memory");   // own ds_reads landed
    __builtin_amdgcn_sched_barrier(0);
    __builtin_amdgcn_s_barrier();                        // buf[cur] free for reuse
    cur ^= 1;
  }

  const float inv2048 = 1.0f / 2048.0f;
  #pragma unroll
  for (int mt = 0; mt < 2; mt++)
    #pragma unroll
    for (int r = 0; r < 4; r++) {
      int row = m0 + wm + mt*16 + quad*4 + r;
      #pragma unroll
      for (int nt = 0; nt < 4; nt++) {
        int c = wn + nt*16 + l15;
        float v = accM[mt][nt][r] + accC[mt][nt][r]*inv2048 + biasp[c];
        if (MODE == 1) v += resid[(size_t)row*1024 + dcol0 + c];
        dst[(size_t)row*ld + dcol0 + c] = v;
      }
    }
}

// ---------------- MFMA windowed attention ----------------
// Epilogue writes split-f16 (hi, lo*2048) for the Wo DMA GEMM.
__global__ __launch_bounds__(256, 2) void attn_mfma(
    const float* __restrict__ Qs, const float* __restrict__ Kf, const float* __restrict__ Vf,
    _Float16* __restrict__ Oh, _Float16* __restrict__ Ol) {
  int qb = blockIdx.x, n = blockIdx.y;
  int b = blockIdx.z >> 4, h = blockIdx.z & 15;
  int g = h & 1;
  int tid = threadIdx.x;
  int lane = tid & 63, w = tid >> 6;
  int l15 = lane & 15, quad = lane >> 4;

  __shared__ __align__(16) char smem[70912];
  _Float16* Vt = (_Float16*)smem;                 // [64][264]
  _Float16* Qh = (_Float16*)(smem + 33792);       // [64][72]
  _Float16* Ql = (_Float16*)(smem + 43008);
  _Float16* Kh = (_Float16*)(smem + 52224);
  _Float16* Kl = (_Float16*)(smem + 61440);
  _Float16* Pm = (_Float16*)(smem + 33792);       // alias over Q/K
  float*   linv = (float*)(smem + 70656);

  int qtok0 = b*4096 + n*128 + qb*64;
  int key0  = b*4096 + n*128;

  #pragma unroll
  for (int i = 0; i < 4; i++) {
    int idx = tid + 256*i;
    int row = idx >> 4, c4 = idx & 15;
    float4 v = *(const float4*)&Qs[(size_t)(qtok0+row)*1024 + h*64 + c4*4];
    f16x4 hv, lv;
    hv.x = (_Float16)v.x; lv.x = (_Float16)(v.x - (float)hv.x);
    hv.y = (_Float16)v.y; lv.y = (_Float16)(v.y - (float)hv.y);
    hv.z = (_Float16)v.z; lv.z = (_Float16)(v.z - (float)hv.z);
    hv.w = (_Float16)v.w; lv.w = (_Float16)(v.w - (float)hv.w);
    *(f16x4*)&Qh[row*72 + c4*4] = hv;
    *(f16x4*)&Ql[row*72 + c4*4] = lv;
  }
  {
    int kk = tid >> 4, dd = tid & 15;
    #pragma unroll
    for (int i = 0; i < 8; i++) {
      int p = i*16 + kk;
      float4 v0 = *(const float4*)&Vf[(size_t)(key0 + 2*p    )*128 + g*64 + dd*4];
      float4 v1 = *(const float4*)&Vf[(size_t)(key0 + 2*p + 1)*128 + g*64 + dd*4];
      *(unsigned*)&Vt[(dd*4+0)*264 + 2*p] = pk2(v0.x, v1.x);
      *(unsigned*)&Vt[(dd*4+1)*264 + 2*p] = pk2(v0.y, v1.y);
      *(unsigned*)&Vt[(dd*4+2)*264 + 2*p] = pk2(v0.z, v1.z);
      *(unsigned*)&Vt[(dd*4+3)*264 + 2*p] = pk2(v0.w, v1.w);
    }
  }
  __syncthreads();

  f16x8 qh[2], ql[2];
  {
    int qrow = (w*16 + l15)*72;
    qh[0] = *(const f16x8*)&Qh[qrow + quad*8];
    qh[1] = *(const f16x8*)&Qh[qrow + 32 + quad*8];
    ql[0] = *(const f16x8*)&Ql[qrow + quad*8];
    ql[1] = *(const f16x8*)&Ql[qrow + 32 + quad*8];
  }

  f32x4 S[16];
  #pragma unroll
  for (int t = 0; t < 16; t++) S[t] = (f32x4){0.f,0.f,0.f,0.f};

  for (int c = 0; c < 4; c++) {
    if (c) __syncthreads();
    #pragma unroll
    for (int i = 0; i < 4; i++) {
      int idx = tid + 256*i;
      int row = idx >> 4, c4 = idx & 15;
      float4 v = *(const float4*)&Kf[(size_t)(key0 + c*64 + row)*128 + g*64 + c4*4];
      f16x4 hv, lv;
      hv.x = (_Float16)v.x; lv.x = (_Float16)(v.x - (float)hv.x);
      hv.y = (_Float16)v.y; lv.y = (_Float16)(v.y - (float)hv.y);
      hv.z = (_Float16)v.z; lv.z = (_Float16)(v.z - (float)hv.z);
      hv.w = (_Float16)v.w; lv.w = (_Float16)(v.w - (float)hv.w);
      *(f16x4*)&Kh[row*72 + c4*4] = hv;
      *(f16x4*)&Kl[row*72 + c4*4] = lv;
    }
    __syncthreads();
    #pragma unroll
    for (int t = 0; t < 4; t++) {
      int krow = (t*16 + l15)*72;
      f16x8 kh0 = *(const f16x8*)&Kh[krow + quad*8];
      f16x8 kh1 = *(const f16x8*)&Kh[krow + 32 + quad*8];
      f16x8 kl0 = *(const f16x8*)&Kl[krow + quad*8];
      f16x8 kl1 = *(const f16x8*)&Kl[krow + 32 + quad*8];
      int ti = c*4 + t;
      S[ti] = __builtin_amdgcn_mfma_f32_16x16x32_f16(qh[0], kh0, S[ti], 0, 0, 0);
      S[ti] = __builtin_amdgcn_mfma_f32_16x16x32_f16(ql[0], kh0, S[ti], 0, 0, 0);
      S[ti] = __builtin_amdgcn_mfma_f32_16x16x32_f16(qh[0], kl0, S[ti], 0, 0, 0);
      S[ti] = __builtin_amdgcn_mfma_f32_16x16x32_f16(qh[1], kh1, S[ti], 0, 0, 0);
      S[ti] = __builtin_amdgcn_mfma_f32_16x16x32_f16(ql[1], kh1, S[ti], 0, 0, 0);
      S[ti] = __builtin_amdgcn_mfma_f32_16x16x32_f16(qh[1], kl1, S[ti], 0, 0, 0);
    }
  }

  float lrow[4];
  #pragma unroll
  for (int r = 0; r < 4; r++) {
    float mx = S[0][r];
    #pragma unroll
    for (int t = 1; t < 16; t++) mx = fmaxf(mx, S[t][r]);
    mx = fmaxf(mx, __shfl_xor(mx, 1)); mx = fmaxf(mx, __shfl_xor(mx, 2));
    mx = fmaxf(mx, __shfl_xor(mx, 4)); mx = fmaxf(mx, __shfl_xor(mx, 8));
    float sum = 0.f;
    #pragma unroll
    for (int t = 0; t < 16; t++) {
      float e = __expf((S[t][r] - mx) * 0.125f);
      S[t][r] = e; sum += e;
    }
    sum += __shfl_xor(sum, 1); sum += __shfl_xor(sum, 2);
    sum += __shfl_xor(sum, 4); sum += __shfl_xor(sum, 8);
    lrow[r] = sum;
  }
  if (l15 == 0) {
    #pragma unroll
    for (int r = 0; r < 4; r++) linv[w*16 + quad*4 + r] = 1.f / lrow[r];
  }
  __syncthreads();

  #pragma unroll
  for (int r = 0; r < 4; r++) {
    int q = w*16 + quad*4 + r;
    bool mine = (l15 & 1) ? (r >= 2) : (r < 2);
    #pragma unroll
    for (int t = 0; t < 16; t++) {
      float own = S[t][r];
      float oth = __shfl_xor(own, 1);
      if (mine) {
        float e0 = (l15 & 1) ? oth : own;
        float e1 = (l15 & 1) ? own : oth;
        *(unsigned*)&Pm[q*264 + t*16 + (l15 & ~1)] = pk2(e0, e1);
      }
    }
  }
  __syncthreads();

  f32x4 O[4];
  #pragma unroll
  for (int t = 0; t < 4; t++) O[t] = (f32x4){0.f,0.f,0.f,0.f};
  {
    int prow = (w*16 + l15)*264;
    #pragma unroll
    for (int ks = 0; ks < 8; ks++) {
      f16x8 pa = *(const f16x8*)&Pm[prow + ks*32 + quad*8];
      #pragma unroll
      for (int t = 0; t < 4; t++) {
        f16x8 vb = *(const f16x8*)&Vt[(t*16 + l15)*264 + ks*32 + quad*8];
        O[t] = __builtin_amdgcn_mfma_f32_16x16x32_f16(pa, vb, O[t], 0, 0, 0);
      }
    }
  }

  #pragma unroll
  for (int r = 0; r < 4; r++) {
    int qlocal = w*16 + quad*4 + r;
    float inv = linv[qlocal];
    int orow = b*4096 + n*256 + qb*64 + qlocal;
    #pragma unroll
    for (int t = 0; t < 4; t++) {
      float o = O[t][r] * inv;
      _Float16 oh = (_Float16)o;
      _Float16 ol = (_Float16)((o - (float)oh) * 2048.f);
      size_t oo = (size_t)orow*1024 + h*64 + t*16 + l15;
      Oh[oo] = oh; Ol[oo] = ol;
    }
  }
}

// ---------------- fused LN2 + gating: one pass over h ----------------
__global__ __launch_bounds__(256) void ln2_gating(
    const float* __restrict__ h,
    const float* __restrict__ g2, const float* __restrict__ b2,
    const float* __restrict__ Wg, const float* __restrict__ bg,
    short* __restrict__ hln,
    int* __restrict__ e1e2, float2* __restrict__ p12, float* __restrict__ entArr) {
  int tid = threadIdx.x, lane = tid & 63, wid = tid >> 6;
  int tok = blockIdx.x*4 + wid;
  const float* row = h + (size_t)tok * 1024;
  float4 xv4[4];
  float s = 0.f, s2 = 0.f;
  #pragma unroll
  for (int q = 0; q < 4; q++) {
    float4 xv = ((const float4*)row)[lane*4 + q];
    xv4[q] = xv;
    s  += xv.x + xv.y + xv.z + xv.w;
    s2 += xv.x*xv.x + xv.y*xv.y + xv.z*xv.z + xv.w*xv.w;
  }
  s = wave_sum64(s); s2 = wave_sum64(s2);
  float mu = s * (1.f/1024.f);
  float var = s2 * (1.f/1024.f) - mu*mu;
  float rs = rsqrtf(var + 1e-5f);
  double mud = (double)mu, rsd = (double)rs;
  double acc[8] = {};
  short* hrow = hln + (size_t)tok * 1024;
  #pragma unroll
  for (int q = 0; q < 4; q++) {
    float4 xv = xv4[q];
    float4 gv = ((const float4*)g2)[lane*4 + q];
    float4 bv = ((const float4*)b2)[lane*4 + q];
    float xs[4] = {xv.x, xv.y, xv.z, xv.w};
    float gs[4] = {gv.x, gv.y, gv.z, gv.w};
    float bs[4] = {bv.x, bv.y, bv.z, bv.w};
    short os[4];
    #pragma unroll
    for (int j = 0; j < 4; j++) {
      int i = lane*16 + q*4 + j;
      os[j] = f2bf((xs[j] - mu) * rs * gs[j] + bs[j]);
      double xn = ((double)xs[j] - mud) * rsd * (double)gs[j] + (double)bs[j];
      const float4 w0 = *(const float4*)&Wg[(size_t)i*8];
      const float4 w1 = *(const float4*)&Wg[(size_t)i*8 + 4];
      acc[0] += xn*(double)w0.x; acc[1] += xn*(double)w0.y;
      acc[2] += xn*(double)w0.z; acc[3] += xn*(double)w0.w;
      acc[4] += xn*(double)w1.x; acc[5] += xn*(double)w1.y;
      acc[6] += xn*(double)w1.z; acc[7] += xn*(double)w1.w;
    }
    short4 o = make_short4(os[0], os[1], os[2], os[3]);
    ((short4*)hrow)[lane*4 + q] = o;
  }
  #pragma unroll
  for (int e = 0; e < 8; e++) acc[e] = wave_sum64d(acc[e]) + (double)bg[e];
  int e1 = 0;
  #pragma unroll
  for (int e = 1; e < 8; e++) if (acc[e] > acc[e1]) e1 = e;
  int e2 = (e1 == 0) ? 1 : 0;
  #pragma unroll
  for (int e = 0; e < 8; e++) if (e != e1 && acc[e] > acc[e2]) e2 = e;
  float lf[8];
  #pragma unroll
  for (int e = 0; e < 8; e++) lf[e] = (float)acc[e];
  float mx = lf[0];
  #pragma unroll
  for (int e = 1; e < 8; e++) mx = fmaxf(mx, lf[e]);
  float ex[8], Z = 0.f;
  #pragma unroll
  for (int e = 0; e < 8; e++) { ex[e] = __expf(lf[e] - mx); Z += ex[e]; }
  float invZ = 1.f / Z, ent = 0.f;
  float p[8];
  #pragma unroll
  for (int e = 0; e < 8; e++) { p[e] = ex[e]*invZ; ent -= p[e]*__logf(p[e] + 1e-8f); }
  if (lane == 0) {
    e1e2[tok] = e1 | (e2 << 8);
    p12[tok]  = make_float2(p[e1], p[e2]);
    entArr[tok] = ent;
  }
}

// ---------------- gating phase 2: LDS-aggregated scatter ----------------
__global__ __launch_bounds__(128) void scatter_kernel(
    const int* __restrict__ e1e2, const float2* __restrict__ p12,
    int* __restrict__ cnt, int* __restrict__ bucket, float* __restrict__ bucketP,
    int* __restrict__ bucketS) {
  __shared__ int lcnt[8], base[8];
  int tid = threadIdx.x;
  if (tid < 8) lcnt[tid] = 0;
  __syncthreads();
  int tok = blockIdx.x*128 + tid;
  int ee = e1e2[tok];
  int e1 = ee & 255, e2 = ee >> 8;
  float2 p = p12[tok];
  int o1 = atomicAdd(&lcnt[e1], 1);
  int o2 = atomicAdd(&lcnt[e2], 1);
  __syncthreads();
  if (tid < 8) base[tid] = atomicAdd(&cnt[tid], lcnt[tid]);
  __syncthreads();
  int i1 = base[e1] + o1;
  bucket[e1*8192 + i1] = tok; bucketP[e1*8192 + i1] = p.x; bucketS[e1*8192 + i1] = 0;
  int i2 = base[e2] + o2;
  bucket[e2*8192 + i2] = tok; bucketP[e2*8192 + i2] = p.y; bucketS[e2*8192 + i2] = 1;
}

__global__ __launch_bounds__(256) void aux_kernel(const float* __restrict__ entArr,
    const int* __restrict__ cnt, float* __restrict__ auxOut) {
  int tid = threadIdx.x;
  float s = 0.f;
  for (int i = tid; i < 8192; i += 256) s += entArr[i];
  s = wave_sum64(s);
  __shared__ float pa[4];
  if ((tid & 63) == 0) pa[tid >> 6] = s;
  __syncthreads();
  if (tid == 0) {
    float tot = pa[0]+pa[1]+pa[2]+pa[3];
    float entMean = tot / 8192.f;
    float pen = 0.f;
    for (int e = 0; e < 8; e++) {
      float usage = (float)cnt[e] / (8192.f + 1e-8f);
      pen += fmaxf(usage - 0.4f, 0.f);
    }
    auxOut[0] = 0.05f * entMean + pen;
  }
}

// ---------------- We transpose (fp32 -> bf16, per expert) ----------------
__global__ void transpose_We(const float* __restrict__ We, short* __restrict__ WeT) {
  int e = blockIdx.z;
  __shared__ float tile[32][33];
  int kt = blockIdx.x, nt = blockIdx.y;
  int tx = threadIdx.x, ty = threadIdx.y;
  const float* src = We + (size_t)e * 1048576;
  short* dst = WeT + (size_t)e * 1048576;
  #pragma unroll
  for (int i = 0; i < 4; i++)
    tile[ty + 8*i][tx] = src[(size_t)(kt*32 + ty + 8*i)*1024 + nt*32 + tx];
  __syncthreads();
  #pragma unroll
  for (int i = 0; i < 4; i++)
    dst[(size_t)(nt*32 + ty + 8*i)*1024 + kt*32 + tx] = f2bf(tile[tx][ty + 8*i]);
}

// ---------------- bf16 MFMA grouped MoE GEMM (128x256 tile, BK=32 dbuf, grid-stride, counted vmcnt) ----------------
// Epilogue writes f16 slots (halves combine traffic). T5 setprio around compute phase.
__global__ __launch_bounds__(256, 2) void moe_gemm(
    const short* __restrict__ hln, const short* __restrict__ WeT,
    const float* __restrict__ be, const int* __restrict__ cnt,
    const int* __restrict__ bucket, const float* __restrict__ bucketP,
    const int* __restrict__ bucketS,
    _Float16* __restrict__ slot0, _Float16* __restrict__ slot1) {
  int e = blockIdx.z;
  int count = cnt[e];
  int n0 = blockIdx.y * 256;
  __shared__ short As[2][4096];   // [128][32] swizzled bf16
  __shared__ short Bs[2][8192];   // [256][32] swizzled bf16
  __shared__ int   toks[128];
  __shared__ float pws[128];
  __shared__ int   sls[128];
  int tid = threadIdx.x;
  int lane = tid & 63, w = tid >> 6;
  int wm = (w & 1) * 64, wn = (w >> 1) * 128;
  int l15 = lane & 15, quad = lane >> 4;
  const short* Bt = WeT + (size_t)e * 1048576;

  // A staging: 512 chunks (2/thread); B staging: 1024 chunks (4/thread).
  int PA0 = tid, PA1 = tid + 256;
  int cA0 = (PA0 & 3) ^ ((PA0 >> 3) & 3);
  int cA1 = (PA1 & 3) ^ ((PA1 >> 3) & 3);
  int PB[4]; size_t gB[4];
  #pragma unroll
  for (int j = 0; j < 4; j++) {
    PB[j] = tid + 256*j;
    int cb = (PB[j] & 3) ^ ((PB[j] >> 3) & 3);
    gB[j] = (size_t)(n0 + (PB[j] >> 2)) * 1024 + cb * 8;
  }

  for (int mtile = blockIdx.x; mtile * 128 < count; mtile += 16) {
    __syncthreads();   // guard toks/LDS reuse across mtile iterations
    if (tid < 128) {
      int idx = mtile*128 + tid;
      int ic = idx < count ? idx : count - 1;
      toks[tid] = bucket[e*8192 + ic];
      pws[tid]  = bucketP[e*8192 + ic];
      sls[tid]  = bucketS[e*8192 + ic];
    }
    __syncthreads();

    size_t gA0 = (size_t)toks[PA0 >> 2] * 1024 + cA0 * 8;
    size_t gA1 = (size_t)toks[PA1 >> 2] * 1024 + cA1 * 8;

    f32x4 acc[4][8] = {};

    // prologue: stage K-slice 0 into buffer 0 (6 loads/thread)
    gld16(hln + gA0, &As[0][PA0*8]);
    gld16(hln + gA1, &As[0][PA1*8]);
    #pragma unroll
    for (int j = 0; j < 4; j++) gld16(Bt + gB[j], &Bs[0][PB[j]*8]);

    int cur = 0;
    for (int it = 0; it < 32; ++it) {
      if (it < 31) {
        int kb = (it + 1) * 32;
        int nb = cur ^ 1;
        gld16(hln + gA0 + kb, &As[nb][PA0*8]);
        gld16(hln + gA1 + kb, &As[nb][PA1*8]);
        #pragma unroll
        for (int j = 0; j < 4; j++) gld16(Bt + gB[j] + kb, &Bs[nb][PB[j]*8]);
        asm volatile("s_waitcnt vmcnt(6)" ::: "memory");  // loads(it) done; loads(it+1) fly
      } else {
        asm volatile("s_waitcnt vmcnt(0)" ::: "memory");
      }
      __builtin_amdgcn_s_barrier();
      __builtin_amdgcn_sched_barrier(0);
      __builtin_amdgcn_s_setprio(1);
      bf16x8 bfr[8];
      #pragma unroll
      for (int nt = 0; nt < 8; nt++) {
        int row = wn + nt*16 + l15;
        int pc = quad ^ ((row >> 1) & 3);
        bfr[nt] = *(const bf16x8*)&Bs[cur][row*32 + pc*8];
      }
      #pragma unroll
      for (int mt = 0; mt < 4; mt++) {
        int row = wm + mt*16 + l15;
        int pc = quad ^ ((row >> 1) & 3);
        bf16x8 af = *(const bf16x8*)&As[cur][row*32 + pc*8];
        #pragma unroll
        for (int nt = 0; nt < 8; nt++)
          acc[mt][nt] = __builtin_amdgcn_mfma_f32_16x16x32_bf16(af, bfr[nt], acc[mt][nt], 0, 0, 0);
      }
      __builtin_amdgcn_s_setprio(0);
      asm volatile("s_waitcnt lgkmcnt(0)" ::: "memory");
      __builtin_amdgcn_sched_barrier(0);
      __builtin_amdgcn_s_barrier();
      cur ^= 1;
    }

    #pragma unroll
    for (int mt = 0; mt < 4; mt++) {
      #pragma unroll
      for (int r = 0; r < 4; r++) {
        int m = wm + mt*16 + quad*4 + r;
        if (mtile*128 + m < count) {
          int tok = toks[m];
          float pp = pws[m];
          _Float16* dst = sls[m] ? slot1 : slot0;
          #pragma unroll
          for (int nt = 0; nt < 8; nt++) {
            int col = n0 + wn + nt*16 + l15;
            dst[(size_t)tok*1024 + col] = (_Float16)(pp * (acc[mt][nt][r] + be[e*1024 + col]));
          }
        }
      }
    }
  }
}

// ---------------- final combine (f16 slots) ----------------
__global__ __launch_bounds__(256) void final_add(float* __restrict__ out,
    const _Float16* __restrict__ s0, const _Float16* __restrict__ s1) {
  const int total = 8388608 / 8;   // per 8 elements
  for (int i = blockIdx.x*256 + threadIdx.x; i < total; i += gridDim.x*256) {
    f16x8 a0 = ((const f16x8*)s0)[i];
    f16x8 a1 = ((const f16x8*)s1)[i];
    float4 o0 = ((float4*)out)[2*i];
    float4 o1 = ((float4*)out)[2*i + 1];
    o0.x += (float)a0[0] + (float)a1[0]; o0.y += (float)a0[1] + (float)a1[1];
    o0.z += (float)a0[2] + (float)a1[2]; o0.w += (float)a0[3] + (float)a1[3];
    o1.x += (float)a0[4] + (float)a1[4]; o1.y += (float)a0[5] + (float)a1[5];
    o1.z += (float)a0[6] + (float)a1[6]; o1.w += (float)a0[7] + (float)a1[7];
    ((float4*)out)[2*i] = o0;
    ((float4*)out)[2*i + 1] = o1;
  }
}

// ---------------- host launcher ----------------
extern "C" void kernel_launch(void* const* d_in, const int* in_sizes, int n_in,
                              void* d_out, int out_size, void* d_ws, size_t ws_size,
                              hipStream_t stream) {
  const float* x    = (const float*)d_in[0];
  const float* Wq   = (const float*)d_in[1];
  const float* bq   = (const float*)d_in[2];
  const float* Wk   = (const float*)d_in[3];
  const float* bk   = (const float*)d_in[4];
  const float* Wv   = (const float*)d_in[5];
  const float* bv   = (const float*)d_in[6];
  const float* Wo   = (const float*)d_in[7];
  const float* bo   = (const float*)d_in[8];
  const float* ln1g = (const float*)d_in[9];
  const float* ln1b = (const float*)d_in[10];
  const float* ln2g = (const float*)d_in[11];
  const float* ln2b = (const float*)d_in[12];
  const float* Wg   = (const float*)d_in[13];
  const float* bg   = (const float*)d_in[14];
  const float* We   = (const float*)d_in[15];
  const float* be   = (const float*)d_in[16];
  float* out = (float*)d_out;

  char* ws = (char*)d_ws;
  size_t off = 0;
  auto alloc = [&](size_t bytes) { char* p = ws + off; off += (bytes + 255) & ~(size_t)255; return p; };
  _Float16* xh  = (_Float16*)alloc(16777216);  // 8192x1024 f16 (LN1 hi); reused as Oh
  _Float16* xl  = (_Float16*)alloc(16777216);  // (LN1 lo*2048); reused as Ol
  float* Qs    = (float*)alloc(33554432);      // 8192x1024 f32; reused as hln
  float* Kf    = (float*)alloc(4194304);
  float* Vf    = (float*)alloc(4194304);
  short* WeT   = (short*)alloc(16777216);
  float* slot0 = (float*)alloc(33554432);      // f16 use: 16MB; front also WoT scratch
  float* slot1 = (float*)alloc(33554432);      // f16 use: 16MB; front also BTqkv scratch
  int*   bucket  = (int*)alloc(262144);
  float* bucketP = (float*)alloc(262144);
  int*   bucketS = (int*)alloc(262144);
  int*   cnt     = (int*)alloc(256);
  float* entArr  = (float*)alloc(32768);
  int*   e1e2    = (int*)alloc(32768);
  float2* p12    = (float2*)alloc(65536);
  _Float16* Oh = xh;            // alias: xh/xl dead after QKV GEMM
  _Float16* Ol = xl;
  short* hln   = (short*)Qs;    // alias: Qs dead after attention
  _Float16* WoTh    = (_Float16*)slot0;
  _Float16* WoTl    = (_Float16*)(slot0 + 524288);
  _Float16* BTqkv_h = (_Float16*)slot1;
  _Float16* BTqkv_l = (_Float16*)((char*)slot1 + 2621440);

  hipMemsetAsync(cnt, 0, 256, stream);
  t_w_f16<<<dim3(32, 32), dim3(32, 8), 0, stream>>>(Wq, 1024, BTqkv_h, BTqkv_l, 0);
  t_w_f16<<<dim3(32, 4),  dim3(32, 8), 0, stream>>>(Wk, 128,  BTqkv_h, BTqkv_l, 1024);
  t_w_f16<<<dim3(32, 4),  dim3(32, 8), 0, stream>>>(Wv, 128,  BTqkv_h, BTqkv_l, 1152);
  t_w_f16<<<dim3(32, 32), dim3(32, 8), 0, stream>>>(Wo, 1024, WoTh, WoTl, 0);
  transpose_We<<<dim3(32,32,8), dim3(32,8), 0, stream>>>(We, WeT);

  ln_split<<<8192, 256, 0, stream>>>(x, ln1g, ln1b, xh, xl);
  gemm_dma<0><<<dim3(128,10), 256, 0, stream>>>(xh, xl, BTqkv_h, BTqkv_l, bq, bk, bv,
                                                nullptr, Qs, Kf, Vf);
  attn_mfma<<<dim3(4,16,32), 256, 0, stream>>>(Qs, Kf, Vf, Oh, Ol);
  gemm_dma<1><<<dim3(128,8), 256, 0, stream>>>(Oh, Ol, WoTh, WoTl, bo, nullptr, nullptr,
                                               x, out, nullptr, nullptr);
  ln2_gating<<<2048, 256, 0, stream>>>(out, ln2g, ln2b, Wg, bg, hln, e1e2, p12, entArr);
  scatter_kernel<<<64, 128, 0, stream>>>(e1e2, p12, cnt, bucket, bucketP, bucketS);
  aux_kernel<<<1, 256, 0, stream>>>(entArr, cnt, out + 8388608);
  moe_gemm<<<dim3(16,4,8), 256, 0, stream>>>(hln, WeT, be, cnt, bucket, bucketP, bucketS,
                                             (_Float16*)slot0, (_Float16*)slot1);
  final_add<<<2048, 256, 0, stream>>>(out, (const _Float16*)slot0, (const _Float16*)slot1);
}

// Round 13
// 508.519 us; speedup vs baseline: 1.0534x; 1.0534x over previous
//
#include <hip/hip_runtime.h>
#include <hip/hip_bf16.h>
#include <stdint.h>

// ---------------- types / helpers ----------------
typedef __attribute__((ext_vector_type(8))) short bf16x8;
typedef __attribute__((ext_vector_type(8))) _Float16 f16x8;
typedef __attribute__((ext_vector_type(4))) _Float16 f16x4;
typedef __attribute__((ext_vector_type(4))) float f32x4;

__device__ __forceinline__ short f2bf(float f) {
  __hip_bfloat16 h = __float2bfloat16(f);
  union { __hip_bfloat16 h; short s; } u; u.h = h; return u.s;
}

__device__ __forceinline__ unsigned pk2(float a, float b) {
  union { _Float16 h; unsigned short s; } ua, ub;
  ua.h = (_Float16)a; ub.h = (_Float16)b;
  return (unsigned)ua.s | ((unsigned)ub.s << 16);
}

// async global->LDS, 16B per lane. LDS dest must be wave-uniform base + lane*16.
__device__ __forceinline__ void gld16(const void* g, void* l) {
  __builtin_amdgcn_global_load_lds((const __attribute__((address_space(1))) void*)g,
                                   (__attribute__((address_space(3))) void*)l, 16, 0, 0);
}

__device__ __forceinline__ float wave_sum64(float v) {
  #pragma unroll
  for (int off = 1; off < 64; off <<= 1) v += __shfl_xor(v, off);
  return v;
}
__device__ __forceinline__ double wave_sum64d(double v) {
  #pragma unroll
  for (int off = 1; off < 64; off <<= 1) v += __shfl_xor(v, off);
  return v;
}

// ---------------- LN kernels ----------------
// LN1: emits split-f16 (hi, lo*2048) directly for the DMA GEMM.
__global__ __launch_bounds__(256) void ln_split(const float* __restrict__ x,
    const float* __restrict__ g, const float* __restrict__ b,
    _Float16* __restrict__ xh, _Float16* __restrict__ xl) {
  int t = blockIdx.x, tid = threadIdx.x;
  const float4 v = ((const float4*)(x + (size_t)t * 1024))[tid];
  float s = v.x + v.y + v.z + v.w;
  float s2 = v.x*v.x + v.y*v.y + v.z*v.z + v.w*v.w;
  s = wave_sum64(s); s2 = wave_sum64(s2);
  __shared__ float pa[4], pb[4];
  int wid = tid >> 6, lane = tid & 63;
  if (lane == 0) { pa[wid] = s; pb[wid] = s2; }
  __syncthreads();
  float S = pa[0]+pa[1]+pa[2]+pa[3], S2 = pb[0]+pb[1]+pb[2]+pb[3];
  float mu = S * (1.f/1024.f);
  float var = S2 * (1.f/1024.f) - mu*mu;
  float rs = rsqrtf(var + 1e-5f);
  const float4 gv = ((const float4*)g)[tid];
  const float4 bv = ((const float4*)b)[tid];
  float4 o;
  o.x = (v.x-mu)*rs*gv.x + bv.x; o.y = (v.y-mu)*rs*gv.y + bv.y;
  o.z = (v.z-mu)*rs*gv.z + bv.z; o.w = (v.w-mu)*rs*gv.w + bv.w;
  f16x4 hv, lv;
  hv.x = (_Float16)o.x; lv.x = (_Float16)((o.x - (float)hv.x)*2048.f);
  hv.y = (_Float16)o.y; lv.y = (_Float16)((o.y - (float)hv.y)*2048.f);
  hv.z = (_Float16)o.z; lv.z = (_Float16)((o.z - (float)hv.z)*2048.f);
  hv.w = (_Float16)o.w; lv.w = (_Float16)((o.w - (float)hv.w)*2048.f);
  *(f16x4*)&xh[(size_t)t*1024 + tid*4] = hv;
  *(f16x4*)&xl[(size_t)t*1024 + tid*4] = lv;
}

// ---------------- weight transpose + fp16 hi/lo split ----------------
__global__ void t_w_f16(const float* __restrict__ src, int srcN,
                        _Float16* __restrict__ dh, _Float16* __restrict__ dl, int dstRow0) {
  __shared__ float tile[32][33];
  int kt = blockIdx.x, nt = blockIdx.y;
  int tx = threadIdx.x, ty = threadIdx.y;
  #pragma unroll
  for (int i = 0; i < 4; i++)
    tile[ty + 8*i][tx] = src[(size_t)(kt*32 + ty + 8*i)*srcN + nt*32 + tx];
  __syncthreads();
  #pragma unroll
  for (int i = 0; i < 4; i++) {
    float v = tile[tx][ty + 8*i];
    _Float16 h = (_Float16)v;
    _Float16 l = (_Float16)((v - (float)h) * 2048.0f);
    size_t o = (size_t)(dstRow0 + nt*32 + ty + 8*i)*1024 + kt*32 + tx;
    dh[o] = h; dl[o] = l;
  }
}

// ---------------- split-fp16 DMA MFMA GEMM (128x128, BK=32, dbuf, counted-vmcnt) ----------------
// r12 lesson: launch_bounds(256,4) on 64x128 backfired (compiler kept 88 VGPR,
// occ 18%, dur 107) -> reverted to the best-measured 128x128 config (r9/r11, ~90us).
// NEW (r13): grid transposed -- blockIdx.x = N-panel (y), blockIdx.y = M-tile --
// so the blocks sharing an A-panel are ADJACENT in dispatch. Latency argument:
// counted-vmcnt hides ~600cy; HBM miss ~900cy doesn't fit, L2/L3 hit does.
// Better A locality converts unhidden misses to hidden hits (FETCH 53->~43MB).
// Swizzle cp = c ^ ((row>>1)&3): conflict-free (verified r5).
template<int MODE>
__global__ __launch_bounds__(256, 2) void gemm_dma(
    const _Float16* __restrict__ Agh, const _Float16* __restrict__ Agl,
    const _Float16* __restrict__ BTh, const _Float16* __restrict__ BTl,
    const float* __restrict__ b0, const float* __restrict__ b1, const float* __restrict__ b2,
    const float* __restrict__ resid,
    float* __restrict__ out0, float* __restrict__ out1, float* __restrict__ out2) {
  int m0 = blockIdx.y * 128;           // grid transposed: y = M-tile
  int y = blockIdx.x;                  //                  x = N-panel
  int n0 = y * 128;
  float* dst; const float* biasp; int dcol0, ld;
  if (MODE == 0) {
    if (y < 8)      { dst = out0; biasp = b0 + y*128; dcol0 = y*128; ld = 1024; }
    else if (y == 8){ dst = out1; biasp = b1; dcol0 = 0; ld = 128; }
    else            { dst = out2; biasp = b2; dcol0 = 0; ld = 128; }
  } else            { dst = out0; biasp = b0 + y*128; dcol0 = y*128; ld = 1024; }

  __shared__ _Float16 AhS[2][4096];   // [128][32] swizzled
  __shared__ _Float16 AlS[2][4096];
  __shared__ _Float16 BhS[2][4096];   // [128][32] swizzled
  __shared__ _Float16 BlS[2][4096];
  int tid = threadIdx.x;
  int lane = tid & 63, w = tid >> 6;
  int wm = (w & 1) * 64, wn = (w >> 1) * 64;
  int l15 = lane & 15, quad = lane >> 4;

  // Staging geometry (fixed across K): 2 chunks/thread per array (512 chunks each).
  int P0 = tid, P1 = tid + 256;
  int c0 = (P0 & 3) ^ ((P0 >> 3) & 3);
  int c1 = (P1 & 3) ^ ((P1 >> 3) & 3);
  size_t gA0 = (size_t)(m0 + (P0 >> 2)) * 1024 + c0 * 8;
  size_t gA1 = (size_t)(m0 + (P1 >> 2)) * 1024 + c1 * 8;
  size_t gB0 = (size_t)(n0 + (P0 >> 2)) * 1024 + c0 * 8;
  size_t gB1 = (size_t)(n0 + (P1 >> 2)) * 1024 + c1 * 8;

  f32x4 accM[4][4] = {};
  f32x4 accC[4][4] = {};

  // prologue: stage K-tile 0 into buffer 0 (8 loads/thread)
  gld16(Agh + gA0, &AhS[0][P0*8]);
  gld16(Agh + gA1, &AhS[0][P1*8]);
  gld16(Agl + gA0, &AlS[0][P0*8]);
  gld16(Agl + gA1, &AlS[0][P1*8]);
  gld16(BTh + gB0, &BhS[0][P0*8]);
  gld16(BTh + gB1, &BhS[0][P1*8]);
  gld16(BTl + gB0, &BlS[0][P0*8]);
  gld16(BTl + gB1, &BlS[0][P1*8]);

  int cur = 0;
  for (int it = 0; it < 32; ++it) {
    if (it < 31) {
      int kb = (it + 1) * 32;
      int nb = cur ^ 1;
      gld16(Agh + gA0 + kb, &AhS[nb][P0*8]);
      gld16(Agh + gA1 + kb, &AhS[nb][P1*8]);
      gld16(Agl + gA0 + kb, &AlS[nb][P0*8]);
      gld16(Agl + gA1 + kb, &AlS[nb][P1*8]);
      gld16(BTh + gB0 + kb, &BhS[nb][P0*8]);
      gld16(BTh + gB1 + kb, &BhS[nb][P1*8]);
      gld16(BTl + gB0 + kb, &BlS[nb][P0*8]);
      gld16(BTl + gB1 + kb, &BlS[nb][P1*8]);
      asm volatile("s_waitcnt vmcnt(8)" ::: "memory");   // loads(it) done; loads(it+1) fly
    } else {
      asm volatile("s_waitcnt vmcnt(0)" ::: "memory");
    }
    __builtin_amdgcn_s_barrier();
    __builtin_amdgcn_sched_barrier(0);
    __builtin_amdgcn_s_setprio(1);
    f16x8 bh[4], bl[4];
    #pragma unroll
    for (int nt = 0; nt < 4; nt++) {
      int row = wn + nt*16 + l15;
      int pc = quad ^ ((row >> 1) & 3);
      bh[nt] = *(const f16x8*)&BhS[cur][row*32 + pc*8];
      bl[nt] = *(const f16x8*)&BlS[cur][row*32 + pc*8];
    }
    #pragma unroll
    for (int mt = 0; mt < 4; mt++) {
      int row = wm + mt*16 + l15;
      int pc = quad ^ ((row >> 1) & 3);
      f16x8 ah = *(const f16x8*)&AhS[cur][row*32 + pc*8];
      f16x8 al = *(const f16x8*)&AlS[cur][row*32 + pc*8];
      #pragma unroll
      for (int nt = 0; nt < 4; nt++) {
        accM[mt][nt] = __builtin_amdgcn_mfma_f32_16x16x32_f16(ah, bh[nt], accM[mt][nt], 0, 0, 0);
        accC[mt][nt] = __builtin_amdgcn_mfma_f32_16x16x32_f16(ah, bl[nt], accC[mt][nt], 0, 0, 0);
        accC[mt][nt] = __builtin_amdgcn_mfma_f32_16x16x32_f16(al, bh[nt], accC[mt][nt], 0, 0, 0);
      }
    }
    __builtin_amdgcn_s_setprio(0);
    asm volatile("s_waitcnt lgkmcnt(0)" ::: "memory");   // own ds_reads landed
    __builtin_amdgcn_sched_barrier(0);
    __builtin_amdgcn_s_barrier();                        // buf[cur] free for reuse
    cur ^= 1;
  }

  const float inv2048 = 1.0f / 2048.0f;
  #pragma unroll
  for (int mt = 0; mt < 4; mt++)
    #pragma unroll
    for (int r = 0; r < 4; r++) {
      int row = m0 + wm + mt*16 + quad*4 + r;
      #pragma unroll
      for (int nt = 0; nt < 4; nt++) {
        int c = wn + nt*16 + l15;
        float v = accM[mt][nt][r] + accC[mt][nt][r]*inv2048 + biasp[c];
        if (MODE == 1) v += resid[(size_t)row*1024 + dcol0 + c];
        dst[(size_t)row*ld + dcol0 + c] = v;
      }
    }
}

// ---------------- MFMA windowed attention ----------------
// Epilogue writes split-f16 (hi, lo*2048) for the Wo DMA GEMM.
__global__ __launch_bounds__(256, 2) void attn_mfma(
    const float* __restrict__ Qs, const float* __restrict__ Kf, const float* __restrict__ Vf,
    _Float16* __restrict__ Oh, _Float16* __restrict__ Ol) {
  int qb = blockIdx.x, n = blockIdx.y;
  int b = blockIdx.z >> 4, h = blockIdx.z & 15;
  int g = h & 1;
  int tid = threadIdx.x;
  int lane = tid & 63, w = tid >> 6;
  int l15 = lane & 15, quad = lane >> 4;

  __shared__ __align__(16) char smem[70912];
  _Float16* Vt = (_Float16*)smem;                 // [64][264]
  _Float16* Qh = (_Float16*)(smem + 33792);       // [64][72]
  _Float16* Ql = (_Float16*)(smem + 43008);
  _Float16* Kh = (_Float16*)(smem + 52224);
  _Float16* Kl = (_Float16*)(smem + 61440);
  _Float16* Pm = (_Float16*)(smem + 33792);       // alias over Q/K
  float*   linv = (float*)(smem + 70656);

  int qtok0 = b*4096 + n*128 + qb*64;
  int key0  = b*4096 + n*128;

  #pragma unroll
  for (int i = 0; i < 4; i++) {
    int idx = tid + 256*i;
    int row = idx >> 4, c4 = idx & 15;
    float4 v = *(const float4*)&Qs[(size_t)(qtok0+row)*1024 + h*64 + c4*4];
    f16x4 hv, lv;
    hv.x = (_Float16)v.x; lv.x = (_Float16)(v.x - (float)hv.x);
    hv.y = (_Float16)v.y; lv.y = (_Float16)(v.y - (float)hv.y);
    hv.z = (_Float16)v.z; lv.z = (_Float16)(v.z - (float)hv.z);
    hv.w = (_Float16)v.w; lv.w = (_Float16)(v.w - (float)hv.w);
    *(f16x4*)&Qh[row*72 + c4*4] = hv;
    *(f16x4*)&Ql[row*72 + c4*4] = lv;
  }
  {
    int kk = tid >> 4, dd = tid & 15;
    #pragma unroll
    for (int i = 0; i < 8; i++) {
      int p = i*16 + kk;
      float4 v0 = *(const float4*)&Vf[(size_t)(key0 + 2*p    )*128 + g*64 + dd*4];
      float4 v1 = *(const float4*)&Vf[(size_t)(key0 + 2*p + 1)*128 + g*64 + dd*4];
      *(unsigned*)&Vt[(dd*4+0)*264 + 2*p] = pk2(v0.x, v1.x);
      *(unsigned*)&Vt[(dd*4+1)*264 + 2*p] = pk2(v0.y, v1.y);
      *(unsigned*)&Vt[(dd*4+2)*264 + 2*p] = pk2(v0.z, v1.z);
      *(unsigned*)&Vt[(dd*4+3)*264 + 2*p] = pk2(v0.w, v1.w);
    }
  }
  __syncthreads();

  f16x8 qh[2], ql[2];
  {
    int qrow = (w*16 + l15)*72;
    qh[0] = *(const f16x8*)&Qh[qrow + quad*8];
    qh[1] = *(const f16x8*)&Qh[qrow + 32 + quad*8];
    ql[0] = *(const f16x8*)&Ql[qrow + quad*8];
    ql[1] = *(const f16x8*)&Ql[qrow + 32 + quad*8];
  }

  f32x4 S[16];
  #pragma unroll
  for (int t = 0; t < 16; t++) S[t] = (f32x4){0.f,0.f,0.f,0.f};

  for (int c = 0; c < 4; c++) {
    if (c) __syncthreads();
    #pragma unroll
    for (int i = 0; i < 4; i++) {
      int idx = tid + 256*i;
      int row = idx >> 4, c4 = idx & 15;
      float4 v = *(const float4*)&Kf[(size_t)(key0 + c*64 + row)*128 + g*64 + c4*4];
      f16x4 hv, lv;
      hv.x = (_Float16)v.x; lv.x = (_Float16)(v.x - (float)hv.x);
      hv.y = (_Float16)v.y; lv.y = (_Float16)(v.y - (float)hv.y);
      hv.z = (_Float16)v.z; lv.z = (_Float16)(v.z - (float)hv.z);
      hv.w = (_Float16)v.w; lv.w = (_Float16)(v.w - (float)hv.w);
      *(f16x4*)&Kh[row*72 + c4*4] = hv;
      *(f16x4*)&Kl[row*72 + c4*4] = lv;
    }
    __syncthreads();
    #pragma unroll
    for (int t = 0; t < 4; t++) {
      int krow = (t*16 + l15)*72;
      f16x8 kh0 = *(const f16x8*)&Kh[krow + quad*8];
      f16x8 kh1 = *(const f16x8*)&Kh[krow + 32 + quad*8];
      f16x8 kl0 = *(const f16x8*)&Kl[krow + quad*8];
      f16x8 kl1 = *(const f16x8*)&Kl[krow + 32 + quad*8];
      int ti = c*4 + t;
      S[ti] = __builtin_amdgcn_mfma_f32_16x16x32_f16(qh[0], kh0, S[ti], 0, 0, 0);
      S[ti] = __builtin_amdgcn_mfma_f32_16x16x32_f16(ql[0], kh0, S[ti], 0, 0, 0);
      S[ti] = __builtin_amdgcn_mfma_f32_16x16x32_f16(qh[0], kl0, S[ti], 0, 0, 0);
      S[ti] = __builtin_amdgcn_mfma_f32_16x16x32_f16(qh[1], kh1, S[ti], 0, 0, 0);
      S[ti] = __builtin_amdgcn_mfma_f32_16x16x32_f16(ql[1], kh1, S[ti], 0, 0, 0);
      S[ti] = __builtin_amdgcn_mfma_f32_16x16x32_f16(qh[1], kl1, S[ti], 0, 0, 0);
    }
  }

  float lrow[4];
  #pragma unroll
  for (int r = 0; r < 4; r++) {
    float mx = S[0][r];
    #pragma unroll
    for (int t = 1; t < 16; t++) mx = fmaxf(mx, S[t][r]);
    mx = fmaxf(mx, __shfl_xor(mx, 1)); mx = fmaxf(mx, __shfl_xor(mx, 2));
    mx = fmaxf(mx, __shfl_xor(mx, 4)); mx = fmaxf(mx, __shfl_xor(mx, 8));
    float sum = 0.f;
    #pragma unroll
    for (int t = 0; t < 16; t++) {
      float e = __expf((S[t][r] - mx) * 0.125f);
      S[t][r] = e; sum += e;
    }
    sum += __shfl_xor(sum, 1); sum += __shfl_xor(sum, 2);
    sum += __shfl_xor(sum, 4); sum += __shfl_xor(sum, 8);
    lrow[r] = sum;
  }
  if (l15 == 0) {
    #pragma unroll
    for (int r = 0; r < 4; r++) linv[w*16 + quad*4 + r] = 1.f / lrow[r];
  }
  __syncthreads();

  #pragma unroll
  for (int r = 0; r < 4; r++) {
    int q = w*16 + quad*4 + r;
    bool mine = (l15 & 1) ? (r >= 2) : (r < 2);
    #pragma unroll
    for (int t = 0; t < 16; t++) {
      float own = S[t][r];
      float oth = __shfl_xor(own, 1);
      if (mine) {
        float e0 = (l15 & 1) ? oth : own;
        float e1 = (l15 & 1) ? own : oth;
        *(unsigned*)&Pm[q*264 + t*16 + (l15 & ~1)] = pk2(e0, e1);
      }
    }
  }
  __syncthreads();

  f32x4 O[4];
  #pragma unroll
  for (int t = 0; t < 4; t++) O[t] = (f32x4){0.f,0.f,0.f,0.f};
  {
    int prow = (w*16 + l15)*264;
    #pragma unroll
    for (int ks = 0; ks < 8; ks++) {
      f16x8 pa = *(const f16x8*)&Pm[prow + ks*32 + quad*8];
      #pragma unroll
      for (int t = 0; t < 4; t++) {
        f16x8 vb = *(const f16x8*)&Vt[(t*16 + l15)*264 + ks*32 + quad*8];
        O[t] = __builtin_amdgcn_mfma_f32_16x16x32_f16(pa, vb, O[t], 0, 0, 0);
      }
    }
  }

  #pragma unroll
  for (int r = 0; r < 4; r++) {
    int qlocal = w*16 + quad*4 + r;
    float inv = linv[qlocal];
    int orow = b*4096 + n*256 + qb*64 + qlocal;
    #pragma unroll
    for (int t = 0; t < 4; t++) {
      float o = O[t][r] * inv;
      _Float16 oh = (_Float16)o;
      _Float16 ol = (_Float16)((o - (float)oh) * 2048.f);
      size_t oo = (size_t)orow*1024 + h*64 + t*16 + l15;
      Oh[oo] = oh; Ol[oo] = ol;
    }
  }
}

// ---------------- fused LN2 + gating: one pass over h ----------------
__global__ __launch_bounds__(256) void ln2_gating(
    const float* __restrict__ h,
    const float* __restrict__ g2, const float* __restrict__ b2,
    const float* __restrict__ Wg, const float* __restrict__ bg,
    short* __restrict__ hln,
    int* __restrict__ e1e2, float2* __restrict__ p12, float* __restrict__ entArr) {
  int tid = threadIdx.x, lane = tid & 63, wid = tid >> 6;
  int tok = blockIdx.x*4 + wid;
  const float* row = h + (size_t)tok * 1024;
  float4 xv4[4];
  float s = 0.f, s2 = 0.f;
  #pragma unroll
  for (int q = 0; q < 4; q++) {
    float4 xv = ((const float4*)row)[lane*4 + q];
    xv4[q] = xv;
    s  += xv.x + xv.y + xv.z + xv.w;
    s2 += xv.x*xv.x + xv.y*xv.y + xv.z*xv.z + xv.w*xv.w;
  }
  s = wave_sum64(s); s2 = wave_sum64(s2);
  float mu = s * (1.f/1024.f);
  float var = s2 * (1.f/1024.f) - mu*mu;
  float rs = rsqrtf(var + 1e-5f);
  double mud = (double)mu, rsd = (double)rs;
  double acc[8] = {};
  short* hrow = hln + (size_t)tok * 1024;
  #pragma unroll
  for (int q = 0; q < 4; q++) {
    float4 xv = xv4[q];
    float4 gv = ((const float4*)g2)[lane*4 + q];
    float4 bv = ((const float4*)b2)[lane*4 + q];
    float xs[4] = {xv.x, xv.y, xv.z, xv.w};
    float gs[4] = {gv.x, gv.y, gv.z, gv.w};
    float bs[4] = {bv.x, bv.y, bv.z, bv.w};
    short os[4];
    #pragma unroll
    for (int j = 0; j < 4; j++) {
      int i = lane*16 + q*4 + j;
      os[j] = f2bf((xs[j] - mu) * rs * gs[j] + bs[j]);
      double xn = ((double)xs[j] - mud) * rsd * (double)gs[j] + (double)bs[j];
      const float4 w0 = *(const float4*)&Wg[(size_t)i*8];
      const float4 w1 = *(const float4*)&Wg[(size_t)i*8 + 4];
      acc[0] += xn*(double)w0.x; acc[1] += xn*(double)w0.y;
      acc[2] += xn*(double)w0.z; acc[3] += xn*(double)w0.w;
      acc[4] += xn*(double)w1.x; acc[5] += xn*(double)w1.y;
      acc[6] += xn*(double)w1.z; acc[7] += xn*(double)w1.w;
    }
    short4 o = make_short4(os[0], os[1], os[2], os[3]);
    ((short4*)hrow)[lane*4 + q] = o;
  }
  #pragma unroll
  for (int e = 0; e < 8; e++) acc[e] = wave_sum64d(acc[e]) + (double)bg[e];
  int e1 = 0;
  #pragma unroll
  for (int e = 1; e < 8; e++) if (acc[e] > acc[e1]) e1 = e;
  int e2 = (e1 == 0) ? 1 : 0;
  #pragma unroll
  for (int e = 0; e < 8; e++) if (e != e1 && acc[e] > acc[e2]) e2 = e;
  float lf[8];
  #pragma unroll
  for (int e = 0; e < 8; e++) lf[e] = (float)acc[e];
  float mx = lf[0];
  #pragma unroll
  for (int e = 1; e < 8; e++) mx = fmaxf(mx, lf[e]);
  float ex[8], Z = 0.f;
  #pragma unroll
  for (int e = 0; e < 8; e++) { ex[e] = __expf(lf[e] - mx); Z += ex[e]; }
  float invZ = 1.f / Z, ent = 0.f;
  float p[8];
  #pragma unroll
  for (int e = 0; e < 8; e++) { p[e] = ex[e]*invZ; ent -= p[e]*__logf(p[e] + 1e-8f); }
  if (lane == 0) {
    e1e2[tok] = e1 | (e2 << 8);
    p12[tok]  = make_float2(p[e1], p[e2]);
    entArr[tok] = ent;
  }
}

// ---------------- gating phase 2: LDS-aggregated scatter ----------------
__global__ __launch_bounds__(128) void scatter_kernel(
    const int* __restrict__ e1e2, const float2* __restrict__ p12,
    int* __restrict__ cnt, int* __restrict__ bucket, float* __restrict__ bucketP,
    int* __restrict__ bucketS) {
  __shared__ int lcnt[8], base[8];
  int tid = threadIdx.x;
  if (tid < 8) lcnt[tid] = 0;
  __syncthreads();
  int tok = blockIdx.x*128 + tid;
  int ee = e1e2[tok];
  int e1 = ee & 255, e2 = ee >> 8;
  float2 p = p12[tok];
  int o1 = atomicAdd(&lcnt[e1], 1);
  int o2 = atomicAdd(&lcnt[e2], 1);
  __syncthreads();
  if (tid < 8) base[tid] = atomicAdd(&cnt[tid], lcnt[tid]);
  __syncthreads();
  int i1 = base[e1] + o1;
  bucket[e1*8192 + i1] = tok; bucketP[e1*8192 + i1] = p.x; bucketS[e1*8192 + i1] = 0;
  int i2 = base[e2] + o2;
  bucket[e2*8192 + i2] = tok; bucketP[e2*8192 + i2] = p.y; bucketS[e2*8192 + i2] = 1;
}

__global__ __launch_bounds__(256) void aux_kernel(const float* __restrict__ entArr,
    const int* __restrict__ cnt, float* __restrict__ auxOut) {
  int tid = threadIdx.x;
  float s = 0.f;
  for (int i = tid; i < 8192; i += 256) s += entArr[i];
  s = wave_sum64(s);
  __shared__ float pa[4];
  if ((tid & 63) == 0) pa[tid >> 6] = s;
  __syncthreads();
  if (tid == 0) {
    float tot = pa[0]+pa[1]+pa[2]+pa[3];
    float entMean = tot / 8192.f;
    float pen = 0.f;
    for (int e = 0; e < 8; e++) {
      float usage = (float)cnt[e] / (8192.f + 1e-8f);
      pen += fmaxf(usage - 0.4f, 0.f);
    }
    auxOut[0] = 0.05f * entMean + pen;
  }
}

// ---------------- We transpose (fp32 -> bf16, per expert) ----------------
__global__ void transpose_We(const float* __restrict__ We, short* __restrict__ WeT) {
  int e = blockIdx.z;
  __shared__ float tile[32][33];
  int kt = blockIdx.x, nt = blockIdx.y;
  int tx = threadIdx.x, ty = threadIdx.y;
  const float* src = We + (size_t)e * 1048576;
  short* dst = WeT + (size_t)e * 1048576;
  #pragma unroll
  for (int i = 0; i < 4; i++)
    tile[ty + 8*i][tx] = src[(size_t)(kt*32 + ty + 8*i)*1024 + nt*32 + tx];
  __syncthreads();
  #pragma unroll
  for (int i = 0; i < 4; i++)
    dst[(size_t)(nt*32 + ty + 8*i)*1024 + kt*32 + tx] = f2bf(tile[tx][ty + 8*i]);
}

// ---------------- bf16 MFMA grouped MoE GEMM (128x256 tile, BK=32 dbuf, grid-stride, counted vmcnt) ----------------
// Epilogue writes f16 slots (halves combine traffic). T5 setprio around compute phase.
__global__ __launch_bounds__(256, 2) void moe_gemm(
    const short* __restrict__ hln, const short* __restrict__ WeT,
    const float* __restrict__ be, const int* __restrict__ cnt,
    const int* __restrict__ bucket, const float* __restrict__ bucketP,
    const int* __restrict__ bucketS,
    _Float16* __restrict__ slot0, _Float16* __restrict__ slot1) {
  int e = blockIdx.z;
  int count = cnt[e];
  int n0 = blockIdx.y * 256;
  __shared__ short As[2][4096];   // [128][32] swizzled bf16
  __shared__ short Bs[2][8192];   // [256][32] swizzled bf16
  __shared__ int   toks[128];
  __shared__ float pws[128];
  __shared__ int   sls[128];
  int tid = threadIdx.x;
  int lane = tid & 63, w = tid >> 6;
  int wm = (w & 1) * 64, wn = (w >> 1) * 128;
  int l15 = lane & 15, quad = lane >> 4;
  const short* Bt = WeT + (size_t)e * 1048576;

  // A staging: 512 chunks (2/thread); B staging: 1024 chunks (4/thread).
  int PA0 = tid, PA1 = tid + 256;
  int cA0 = (PA0 & 3) ^ ((PA0 >> 3) & 3);
  int cA1 = (PA1 & 3) ^ ((PA1 >> 3) & 3);
  int PB[4]; size_t gB[4];
  #pragma unroll
  for (int j = 0; j < 4; j++) {
    PB[j] = tid + 256*j;
    int cb = (PB[j] & 3) ^ ((PB[j] >> 3) & 3);
    gB[j] = (size_t)(n0 + (PB[j] >> 2)) * 1024 + cb * 8;
  }

  for (int mtile = blockIdx.x; mtile * 128 < count; mtile += 16) {
    __syncthreads();   // guard toks/LDS reuse across mtile iterations
    if (tid < 128) {
      int idx = mtile*128 + tid;
      int ic = idx < count ? idx : count - 1;
      toks[tid] = bucket[e*8192 + ic];
      pws[tid]  = bucketP[e*8192 + ic];
      sls[tid]  = bucketS[e*8192 + ic];
    }
    __syncthreads();

    size_t gA0 = (size_t)toks[PA0 >> 2] * 1024 + cA0 * 8;
    size_t gA1 = (size_t)toks[PA1 >> 2] * 1024 + cA1 * 8;

    f32x4 acc[4][8] = {};

    // prologue: stage K-slice 0 into buffer 0 (6 loads/thread)
    gld16(hln + gA0, &As[0][PA0*8]);
    gld16(hln + gA1, &As[0][PA1*8]);
    #pragma unroll
    for (int j = 0; j < 4; j++) gld16(Bt + gB[j], &Bs[0][PB[j]*8]);

    int cur = 0;
    for (int it = 0; it < 32; ++it) {
      if (it < 31) {
        int kb = (it + 1) * 32;
        int nb = cur ^ 1;
        gld16(hln + gA0 + kb, &As[nb][PA0*8]);
        gld16(hln + gA1 + kb, &As[nb][PA1*8]);
        #pragma unroll
        for (int j = 0; j < 4; j++) gld16(Bt + gB[j] + kb, &Bs[nb][PB[j]*8]);
        asm volatile("s_waitcnt vmcnt(6)" ::: "memory");  // loads(it) done; loads(it+1) fly
      } else {
        asm volatile("s_waitcnt vmcnt(0)" ::: "memory");
      }
      __builtin_amdgcn_s_barrier();
      __builtin_amdgcn_sched_barrier(0);
      __builtin_amdgcn_s_setprio(1);
      bf16x8 bfr[8];
      #pragma unroll
      for (int nt = 0; nt < 8; nt++) {
        int row = wn + nt*16 + l15;
        int pc = quad ^ ((row >> 1) & 3);
        bfr[nt] = *(const bf16x8*)&Bs[cur][row*32 + pc*8];
      }
      #pragma unroll
      for (int mt = 0; mt < 4; mt++) {
        int row = wm + mt*16 + l15;
        int pc = quad ^ ((row >> 1) & 3);
        bf16x8 af = *(const bf16x8*)&As[cur][row*32 + pc*8];
        #pragma unroll
        for (int nt = 0; nt < 8; nt++)
          acc[mt][nt] = __builtin_amdgcn_mfma_f32_16x16x32_bf16(af, bfr[nt], acc[mt][nt], 0, 0, 0);
      }
      __builtin_amdgcn_s_setprio(0);
      asm volatile("s_waitcnt lgkmcnt(0)" ::: "memory");
      __builtin_amdgcn_sched_barrier(0);
      __builtin_amdgcn_s_barrier();
      cur ^= 1;
    }

    #pragma unroll
    for (int mt = 0; mt < 4; mt++) {
      #pragma unroll
      for (int r = 0; r < 4; r++) {
        int m = wm + mt*16 + quad*4 + r;
        if (mtile*128 + m < count) {
          int tok = toks[m];
          float pp = pws[m];
          _Float16* dst = sls[m] ? slot1 : slot0;
          #pragma unroll
          for (int nt = 0; nt < 8; nt++) {
            int col = n0 + wn + nt*16 + l15;
            dst[(size_t)tok*1024 + col] = (_Float16)(pp * (acc[mt][nt][r] + be[e*1024 + col]));
          }
        }
      }
    }
  }
}

// ---------------- final combine (f16 slots) ----------------
__global__ __launch_bounds__(256) void final_add(float* __restrict__ out,
    const _Float16* __restrict__ s0, const _Float16* __restrict__ s1) {
  const int total = 8388608 / 8;   // per 8 elements
  for (int i = blockIdx.x*256 + threadIdx.x; i < total; i += gridDim.x*256) {
    f16x8 a0 = ((const f16x8*)s0)[i];
    f16x8 a1 = ((const f16x8*)s1)[i];
    float4 o0 = ((float4*)out)[2*i];
    float4 o1 = ((float4*)out)[2*i + 1];
    o0.x += (float)a0[0] + (float)a1[0]; o0.y += (float)a0[1] + (float)a1[1];
    o0.z += (float)a0[2] + (float)a1[2]; o0.w += (float)a0[3] + (float)a1[3];
    o1.x += (float)a0[4] + (float)a1[4]; o1.y += (float)a0[5] + (float)a1[5];
    o1.z += (float)a0[6] + (float)a1[6]; o1.w += (float)a0[7] + (float)a1[7];
    ((float4*)out)[2*i] = o0;
    ((float4*)out)[2*i + 1] = o1;
  }
}

// ---------------- host launcher ----------------
extern "C" void kernel_launch(void* const* d_in, const int* in_sizes, int n_in,
                              void* d_out, int out_size, void* d_ws, size_t ws_size,
                              hipStream_t stream) {
  const float* x    = (const float*)d_in[0];
  const float* Wq   = (const float*)d_in[1];
  const float* bq   = (const float*)d_in[2];
  const float* Wk   = (const float*)d_in[3];
  const float* bk   = (const float*)d_in[4];
  const float* Wv   = (const float*)d_in[5];
  const float* bv   = (const float*)d_in[6];
  const float* Wo   = (const float*)d_in[7];
  const float* bo   = (const float*)d_in[8];
  const float* ln1g = (const float*)d_in[9];
  const float* ln1b = (const float*)d_in[10];
  const float* ln2g = (const float*)d_in[11];
  const float* ln2b = (const float*)d_in[12];
  const float* Wg   = (const float*)d_in[13];
  const float* bg   = (const float*)d_in[14];
  const float* We   = (const float*)d_in[15];
  const float* be   = (const float*)d_in[16];
  float* out = (float*)d_out;

  char* ws = (char*)d_ws;
  size_t off = 0;
  auto alloc = [&](size_t bytes) { char* p = ws + off; off += (bytes + 255) & ~(size_t)255; return p; };
  _Float16* xh  = (_Float16*)alloc(16777216);  // 8192x1024 f16 (LN1 hi); reused as Oh
  _Float16* xl  = (_Float16*)alloc(16777216);  // (LN1 lo*2048); reused as Ol
  float* Qs    = (float*)alloc(33554432);      // 8192x1024 f32; reused as hln
  float* Kf    = (float*)alloc(4194304);
  float* Vf    = (float*)alloc(4194304);
  short* WeT   = (short*)alloc(16777216);
  float* slot0 = (float*)alloc(33554432);      // f16 use: 16MB; front also WoT scratch
  float* slot1 = (float*)alloc(33554432);      // f16 use: 16MB; front also BTqkv scratch
  int*   bucket  = (int*)alloc(262144);
  float* bucketP = (float*)alloc(262144);
  int*   bucketS = (int*)alloc(262144);
  int*   cnt     = (int*)alloc(256);
  float* entArr  = (float*)alloc(32768);
  int*   e1e2    = (int*)alloc(32768);
  float2* p12    = (float2*)alloc(65536);
  _Float16* Oh = xh;            // alias: xh/xl dead after QKV GEMM
  _Float16* Ol = xl;
  short* hln   = (short*)Qs;    // alias: Qs dead after attention
  _Float16* WoTh    = (_Float16*)slot0;
  _Float16* WoTl    = (_Float16*)(slot0 + 524288);
  _Float16* BTqkv_h = (_Float16*)slot1;
  _Float16* BTqkv_l = (_Float16*)((char*)slot1 + 2621440);

  hipMemsetAsync(cnt, 0, 256, stream);
  t_w_f16<<<dim3(32, 32), dim3(32, 8), 0, stream>>>(Wq, 1024, BTqkv_h, BTqkv_l, 0);
  t_w_f16<<<dim3(32, 4),  dim3(32, 8), 0, stream>>>(Wk, 128,  BTqkv_h, BTqkv_l, 1024);
  t_w_f16<<<dim3(32, 4),  dim3(32, 8), 0, stream>>>(Wv, 128,  BTqkv_h, BTqkv_l, 1152);
  t_w_f16<<<dim3(32, 32), dim3(32, 8), 0, stream>>>(Wo, 1024, WoTh, WoTl, 0);
  transpose_We<<<dim3(32,32,8), dim3(32,8), 0, stream>>>(We, WeT);

  ln_split<<<8192, 256, 0, stream>>>(x, ln1g, ln1b, xh, xl);
  gemm_dma<0><<<dim3(10,64), 256, 0, stream>>>(xh, xl, BTqkv_h, BTqkv_l, bq, bk, bv,
                                               nullptr, Qs, Kf, Vf);
  attn_mfma<<<dim3(4,16,32), 256, 0, stream>>>(Qs, Kf, Vf, Oh, Ol);
  gemm_dma<1><<<dim3(8,64), 256, 0, stream>>>(Oh, Ol, WoTh, WoTl, bo, nullptr, nullptr,
                                              x, out, nullptr, nullptr);
  ln2_gating<<<2048, 256, 0, stream>>>(out, ln2g, ln2b, Wg, bg, hln, e1e2, p12, entArr);
  scatter_kernel<<<64, 128, 0, stream>>>(e1e2, p12, cnt, bucket, bucketP, bucketS);
  aux_kernel<<<1, 256, 0, stream>>>(entArr, cnt, out + 8388608);
  moe_gemm<<<dim3(16,4,8), 256, 0, stream>>>(hln, WeT, be, cnt, bucket, bucketP, bucketS,
                                             (_Float16*)slot0, (_Float16*)slot1);
  final_add<<<2048, 256, 0, stream>>>(out, (const _Float16*)slot0, (const _Float16*)slot1);
}

// Round 14
// 503.570 us; speedup vs baseline: 1.0638x; 1.0098x over previous
//
#include <hip/hip_runtime.h>
#include <hip/hip_bf16.h>
#include <stdint.h>

// ---------------- types / helpers ----------------
typedef __attribute__((ext_vector_type(8))) short bf16x8;
typedef __attribute__((ext_vector_type(8))) _Float16 f16x8;
typedef __attribute__((ext_vector_type(4))) _Float16 f16x4;
typedef __attribute__((ext_vector_type(4))) float f32x4;

__device__ __forceinline__ short f2bf(float f) {
  __hip_bfloat16 h = __float2bfloat16(f);
  union { __hip_bfloat16 h; short s; } u; u.h = h; return u.s;
}

__device__ __forceinline__ unsigned pk2(float a, float b) {
  union { _Float16 h; unsigned short s; } ua, ub;
  ua.h = (_Float16)a; ub.h = (_Float16)b;
  return (unsigned)ua.s | ((unsigned)ub.s << 16);
}

// async global->LDS, 16B per lane. LDS dest must be wave-uniform base + lane*16.
__device__ __forceinline__ void gld16(const void* g, void* l) {
  __builtin_amdgcn_global_load_lds((const __attribute__((address_space(1))) void*)g,
                                   (__attribute__((address_space(3))) void*)l, 16, 0, 0);
}

__device__ __forceinline__ float wave_sum64(float v) {
  #pragma unroll
  for (int off = 1; off < 64; off <<= 1) v += __shfl_xor(v, off);
  return v;
}
__device__ __forceinline__ double wave_sum64d(double v) {
  #pragma unroll
  for (int off = 1; off < 64; off <<= 1) v += __shfl_xor(v, off);
  return v;
}

// ---------------- LN kernels ----------------
// LN1: emits split-f16 (hi, lo*2048) directly for the DMA GEMM.
__global__ __launch_bounds__(256) void ln_split(const float* __restrict__ x,
    const float* __restrict__ g, const float* __restrict__ b,
    _Float16* __restrict__ xh, _Float16* __restrict__ xl) {
  int t = blockIdx.x, tid = threadIdx.x;
  const float4 v = ((const float4*)(x + (size_t)t * 1024))[tid];
  float s = v.x + v.y + v.z + v.w;
  float s2 = v.x*v.x + v.y*v.y + v.z*v.z + v.w*v.w;
  s = wave_sum64(s); s2 = wave_sum64(s2);
  __shared__ float pa[4], pb[4];
  int wid = tid >> 6, lane = tid & 63;
  if (lane == 0) { pa[wid] = s; pb[wid] = s2; }
  __syncthreads();
  float S = pa[0]+pa[1]+pa[2]+pa[3], S2 = pb[0]+pb[1]+pb[2]+pb[3];
  float mu = S * (1.f/1024.f);
  float var = S2 * (1.f/1024.f) - mu*mu;
  float rs = rsqrtf(var + 1e-5f);
  const float4 gv = ((const float4*)g)[tid];
  const float4 bv = ((const float4*)b)[tid];
  float4 o;
  o.x = (v.x-mu)*rs*gv.x + bv.x; o.y = (v.y-mu)*rs*gv.y + bv.y;
  o.z = (v.z-mu)*rs*gv.z + bv.z; o.w = (v.w-mu)*rs*gv.w + bv.w;
  f16x4 hv, lv;
  hv.x = (_Float16)o.x; lv.x = (_Float16)((o.x - (float)hv.x)*2048.f);
  hv.y = (_Float16)o.y; lv.y = (_Float16)((o.y - (float)hv.y)*2048.f);
  hv.z = (_Float16)o.z; lv.z = (_Float16)((o.z - (float)hv.z)*2048.f);
  hv.w = (_Float16)o.w; lv.w = (_Float16)((o.w - (float)hv.w)*2048.f);
  *(f16x4*)&xh[(size_t)t*1024 + tid*4] = hv;
  *(f16x4*)&xl[(size_t)t*1024 + tid*4] = lv;
}

// ---------------- weight transpose + fp16 hi/lo split ----------------
__global__ void t_w_f16(const float* __restrict__ src, int srcN,
                        _Float16* __restrict__ dh, _Float16* __restrict__ dl, int dstRow0) {
  __shared__ float tile[32][33];
  int kt = blockIdx.x, nt = blockIdx.y;
  int tx = threadIdx.x, ty = threadIdx.y;
  #pragma unroll
  for (int i = 0; i < 4; i++)
    tile[ty + 8*i][tx] = src[(size_t)(kt*32 + ty + 8*i)*srcN + nt*32 + tx];
  __syncthreads();
  #pragma unroll
  for (int i = 0; i < 4; i++) {
    float v = tile[tx][ty + 8*i];
    _Float16 h = (_Float16)v;
    _Float16 l = (_Float16)((v - (float)h) * 2048.0f);
    size_t o = (size_t)(dstRow0 + nt*32 + ty + 8*i)*1024 + kt*32 + tx;
    dh[o] = h; dl[o] = l;
  }
}

// ---------------- split-fp16 DMA MFMA GEMM (128x128, BK=32, dbuf, counted-vmcnt) ----------------
// r13 lesson (XCD model): workgroups round-robin XCDs by linear id; same-A-panel
// blocks in the x=mtile-fastest layout are spaced 64 (== 0 mod 8) -> SAME XCD L2,
// A fetched once per XCD (53MB). Transposing the grid spread same-A blocks across
// all 8 XCDs -> 3x FETCH, +16us. Keep x = m-tile fastest (r11 config, best: 89.7us).
// T4 counted vmcnt(8); T5 setprio; swizzle cp = c ^ ((row>>1)&3) (0 conflicts, r5).
template<int MODE>
__global__ __launch_bounds__(256, 2) void gemm_dma(
    const _Float16* __restrict__ Agh, const _Float16* __restrict__ Agl,
    const _Float16* __restrict__ BTh, const _Float16* __restrict__ BTl,
    const float* __restrict__ b0, const float* __restrict__ b1, const float* __restrict__ b2,
    const float* __restrict__ resid,
    float* __restrict__ out0, float* __restrict__ out1, float* __restrict__ out2) {
  int m0 = blockIdx.x * 128;
  int y = blockIdx.y;
  int n0 = y * 128;
  float* dst; const float* biasp; int dcol0, ld;
  if (MODE == 0) {
    if (y < 8)      { dst = out0; biasp = b0 + y*128; dcol0 = y*128; ld = 1024; }
    else if (y == 8){ dst = out1; biasp = b1; dcol0 = 0; ld = 128; }
    else            { dst = out2; biasp = b2; dcol0 = 0; ld = 128; }
  } else            { dst = out0; biasp = b0 + y*128; dcol0 = y*128; ld = 1024; }

  __shared__ _Float16 AhS[2][4096];   // [128][32] swizzled
  __shared__ _Float16 AlS[2][4096];
  __shared__ _Float16 BhS[2][4096];   // [128][32] swizzled
  __shared__ _Float16 BlS[2][4096];
  int tid = threadIdx.x;
  int lane = tid & 63, w = tid >> 6;
  int wm = (w & 1) * 64, wn = (w >> 1) * 64;
  int l15 = lane & 15, quad = lane >> 4;

  // Staging geometry (fixed across K): 2 chunks/thread per array (512 chunks each).
  int P0 = tid, P1 = tid + 256;
  int c0 = (P0 & 3) ^ ((P0 >> 3) & 3);
  int c1 = (P1 & 3) ^ ((P1 >> 3) & 3);
  size_t gA0 = (size_t)(m0 + (P0 >> 2)) * 1024 + c0 * 8;
  size_t gA1 = (size_t)(m0 + (P1 >> 2)) * 1024 + c1 * 8;
  size_t gB0 = (size_t)(n0 + (P0 >> 2)) * 1024 + c0 * 8;
  size_t gB1 = (size_t)(n0 + (P1 >> 2)) * 1024 + c1 * 8;

  f32x4 accM[4][4] = {};
  f32x4 accC[4][4] = {};

  // prologue: stage K-tile 0 into buffer 0 (8 loads/thread)
  gld16(Agh + gA0, &AhS[0][P0*8]);
  gld16(Agh + gA1, &AhS[0][P1*8]);
  gld16(Agl + gA0, &AlS[0][P0*8]);
  gld16(Agl + gA1, &AlS[0][P1*8]);
  gld16(BTh + gB0, &BhS[0][P0*8]);
  gld16(BTh + gB1, &BhS[0][P1*8]);
  gld16(BTl + gB0, &BlS[0][P0*8]);
  gld16(BTl + gB1, &BlS[0][P1*8]);

  int cur = 0;
  for (int it = 0; it < 32; ++it) {
    if (it < 31) {
      int kb = (it + 1) * 32;
      int nb = cur ^ 1;
      gld16(Agh + gA0 + kb, &AhS[nb][P0*8]);
      gld16(Agh + gA1 + kb, &AhS[nb][P1*8]);
      gld16(Agl + gA0 + kb, &AlS[nb][P0*8]);
      gld16(Agl + gA1 + kb, &AlS[nb][P1*8]);
      gld16(BTh + gB0 + kb, &BhS[nb][P0*8]);
      gld16(BTh + gB1 + kb, &BhS[nb][P1*8]);
      gld16(BTl + gB0 + kb, &BlS[nb][P0*8]);
      gld16(BTl + gB1 + kb, &BlS[nb][P1*8]);
      asm volatile("s_waitcnt vmcnt(8)" ::: "memory");   // loads(it) done; loads(it+1) fly
    } else {
      asm volatile("s_waitcnt vmcnt(0)" ::: "memory");
    }
    __builtin_amdgcn_s_barrier();
    __builtin_amdgcn_sched_barrier(0);
    __builtin_amdgcn_s_setprio(1);
    f16x8 bh[4], bl[4];
    #pragma unroll
    for (int nt = 0; nt < 4; nt++) {
      int row = wn + nt*16 + l15;
      int pc = quad ^ ((row >> 1) & 3);
      bh[nt] = *(const f16x8*)&BhS[cur][row*32 + pc*8];
      bl[nt] = *(const f16x8*)&BlS[cur][row*32 + pc*8];
    }
    #pragma unroll
    for (int mt = 0; mt < 4; mt++) {
      int row = wm + mt*16 + l15;
      int pc = quad ^ ((row >> 1) & 3);
      f16x8 ah = *(const f16x8*)&AhS[cur][row*32 + pc*8];
      f16x8 al = *(const f16x8*)&AlS[cur][row*32 + pc*8];
      #pragma unroll
      for (int nt = 0; nt < 4; nt++) {
        accM[mt][nt] = __builtin_amdgcn_mfma_f32_16x16x32_f16(ah, bh[nt], accM[mt][nt], 0, 0, 0);
        accC[mt][nt] = __builtin_amdgcn_mfma_f32_16x16x32_f16(ah, bl[nt], accC[mt][nt], 0, 0, 0);
        accC[mt][nt] = __builtin_amdgcn_mfma_f32_16x16x32_f16(al, bh[nt], accC[mt][nt], 0, 0, 0);
      }
    }
    __builtin_amdgcn_s_setprio(0);
    asm volatile("s_waitcnt lgkmcnt(0)" ::: "memory");   // own ds_reads landed
    __builtin_amdgcn_sched_barrier(0);
    __builtin_amdgcn_s_barrier();                        // buf[cur] free for reuse
    cur ^= 1;
  }

  const float inv2048 = 1.0f / 2048.0f;
  #pragma unroll
  for (int mt = 0; mt < 4; mt++)
    #pragma unroll
    for (int r = 0; r < 4; r++) {
      int row = m0 + wm + mt*16 + quad*4 + r;
      #pragma unroll
      for (int nt = 0; nt < 4; nt++) {
        int c = wn + nt*16 + l15;
        float v = accM[mt][nt][r] + accC[mt][nt][r]*inv2048 + biasp[c];
        if (MODE == 1) v += resid[(size_t)row*1024 + dcol0 + c];
        dst[(size_t)row*ld + dcol0 + c] = v;
      }
    }
}

// ---------------- MFMA windowed attention ----------------
// Epilogue writes split-f16 (hi, lo*2048) for the Wo DMA GEMM.
__global__ __launch_bounds__(256, 2) void attn_mfma(
    const float* __restrict__ Qs, const float* __restrict__ Kf, const float* __restrict__ Vf,
    _Float16* __restrict__ Oh, _Float16* __restrict__ Ol) {
  int qb = blockIdx.x, n = blockIdx.y;
  int b = blockIdx.z >> 4, h = blockIdx.z & 15;
  int g = h & 1;
  int tid = threadIdx.x;
  int lane = tid & 63, w = tid >> 6;
  int l15 = lane & 15, quad = lane >> 4;

  __shared__ __align__(16) char smem[70912];
  _Float16* Vt = (_Float16*)smem;                 // [64][264]
  _Float16* Qh = (_Float16*)(smem + 33792);       // [64][72]
  _Float16* Ql = (_Float16*)(smem + 43008);
  _Float16* Kh = (_Float16*)(smem + 52224);
  _Float16* Kl = (_Float16*)(smem + 61440);
  _Float16* Pm = (_Float16*)(smem + 33792);       // alias over Q/K
  float*   linv = (float*)(smem + 70656);

  int qtok0 = b*4096 + n*128 + qb*64;
  int key0  = b*4096 + n*128;

  #pragma unroll
  for (int i = 0; i < 4; i++) {
    int idx = tid + 256*i;
    int row = idx >> 4, c4 = idx & 15;
    float4 v = *(const float4*)&Qs[(size_t)(qtok0+row)*1024 + h*64 + c4*4];
    f16x4 hv, lv;
    hv.x = (_Float16)v.x; lv.x = (_Float16)(v.x - (float)hv.x);
    hv.y = (_Float16)v.y; lv.y = (_Float16)(v.y - (float)hv.y);
    hv.z = (_Float16)v.z; lv.z = (_Float16)(v.z - (float)hv.z);
    hv.w = (_Float16)v.w; lv.w = (_Float16)(v.w - (float)hv.w);
    *(f16x4*)&Qh[row*72 + c4*4] = hv;
    *(f16x4*)&Ql[row*72 + c4*4] = lv;
  }
  {
    int kk = tid >> 4, dd = tid & 15;
    #pragma unroll
    for (int i = 0; i < 8; i++) {
      int p = i*16 + kk;
      float4 v0 = *(const float4*)&Vf[(size_t)(key0 + 2*p    )*128 + g*64 + dd*4];
      float4 v1 = *(const float4*)&Vf[(size_t)(key0 + 2*p + 1)*128 + g*64 + dd*4];
      *(unsigned*)&Vt[(dd*4+0)*264 + 2*p] = pk2(v0.x, v1.x);
      *(unsigned*)&Vt[(dd*4+1)*264 + 2*p] = pk2(v0.y, v1.y);
      *(unsigned*)&Vt[(dd*4+2)*264 + 2*p] = pk2(v0.z, v1.z);
      *(unsigned*)&Vt[(dd*4+3)*264 + 2*p] = pk2(v0.w, v1.w);
    }
  }
  __syncthreads();

  f16x8 qh[2], ql[2];
  {
    int qrow = (w*16 + l15)*72;
    qh[0] = *(const f16x8*)&Qh[qrow + quad*8];
    qh[1] = *(const f16x8*)&Qh[qrow + 32 + quad*8];
    ql[0] = *(const f16x8*)&Ql[qrow + quad*8];
    ql[1] = *(const f16x8*)&Ql[qrow + 32 + quad*8];
  }

  f32x4 S[16];
  #pragma unroll
  for (int t = 0; t < 16; t++) S[t] = (f32x4){0.f,0.f,0.f,0.f};

  for (int c = 0; c < 4; c++) {
    if (c) __syncthreads();
    #pragma unroll
    for (int i = 0; i < 4; i++) {
      int idx = tid + 256*i;
      int row = idx >> 4, c4 = idx & 15;
      float4 v = *(const float4*)&Kf[(size_t)(key0 + c*64 + row)*128 + g*64 + c4*4];
      f16x4 hv, lv;
      hv.x = (_Float16)v.x; lv.x = (_Float16)(v.x - (float)hv.x);
      hv.y = (_Float16)v.y; lv.y = (_Float16)(v.y - (float)hv.y);
      hv.z = (_Float16)v.z; lv.z = (_Float16)(v.z - (float)hv.z);
      hv.w = (_Float16)v.w; lv.w = (_Float16)(v.w - (float)hv.w);
      *(f16x4*)&Kh[row*72 + c4*4] = hv;
      *(f16x4*)&Kl[row*72 + c4*4] = lv;
    }
    __syncthreads();
    #pragma unroll
    for (int t = 0; t < 4; t++) {
      int krow = (t*16 + l15)*72;
      f16x8 kh0 = *(const f16x8*)&Kh[krow + quad*8];
      f16x8 kh1 = *(const f16x8*)&Kh[krow + 32 + quad*8];
      f16x8 kl0 = *(const f16x8*)&Kl[krow + quad*8];
      f16x8 kl1 = *(const f16x8*)&Kl[krow + 32 + quad*8];
      int ti = c*4 + t;
      S[ti] = __builtin_amdgcn_mfma_f32_16x16x32_f16(qh[0], kh0, S[ti], 0, 0, 0);
      S[ti] = __builtin_amdgcn_mfma_f32_16x16x32_f16(ql[0], kh0, S[ti], 0, 0, 0);
      S[ti] = __builtin_amdgcn_mfma_f32_16x16x32_f16(qh[0], kl0, S[ti], 0, 0, 0);
      S[ti] = __builtin_amdgcn_mfma_f32_16x16x32_f16(qh[1], kh1, S[ti], 0, 0, 0);
      S[ti] = __builtin_amdgcn_mfma_f32_16x16x32_f16(ql[1], kh1, S[ti], 0, 0, 0);
      S[ti] = __builtin_amdgcn_mfma_f32_16x16x32_f16(qh[1], kl1, S[ti], 0, 0, 0);
    }
  }

  float lrow[4];
  #pragma unroll
  for (int r = 0; r < 4; r++) {
    float mx = S[0][r];
    #pragma unroll
    for (int t = 1; t < 16; t++) mx = fmaxf(mx, S[t][r]);
    mx = fmaxf(mx, __shfl_xor(mx, 1)); mx = fmaxf(mx, __shfl_xor(mx, 2));
    mx = fmaxf(mx, __shfl_xor(mx, 4)); mx = fmaxf(mx, __shfl_xor(mx, 8));
    float sum = 0.f;
    #pragma unroll
    for (int t = 0; t < 16; t++) {
      float e = __expf((S[t][r] - mx) * 0.125f);
      S[t][r] = e; sum += e;
    }
    sum += __shfl_xor(sum, 1); sum += __shfl_xor(sum, 2);
    sum += __shfl_xor(sum, 4); sum += __shfl_xor(sum, 8);
    lrow[r] = sum;
  }
  if (l15 == 0) {
    #pragma unroll
    for (int r = 0; r < 4; r++) linv[w*16 + quad*4 + r] = 1.f / lrow[r];
  }
  __syncthreads();

  #pragma unroll
  for (int r = 0; r < 4; r++) {
    int q = w*16 + quad*4 + r;
    bool mine = (l15 & 1) ? (r >= 2) : (r < 2);
    #pragma unroll
    for (int t = 0; t < 16; t++) {
      float own = S[t][r];
      float oth = __shfl_xor(own, 1);
      if (mine) {
        float e0 = (l15 & 1) ? oth : own;
        float e1 = (l15 & 1) ? own : oth;
        *(unsigned*)&Pm[q*264 + t*16 + (l15 & ~1)] = pk2(e0, e1);
      }
    }
  }
  __syncthreads();

  f32x4 O[4];
  #pragma unroll
  for (int t = 0; t < 4; t++) O[t] = (f32x4){0.f,0.f,0.f,0.f};
  {
    int prow = (w*16 + l15)*264;
    #pragma unroll
    for (int ks = 0; ks < 8; ks++) {
      f16x8 pa = *(const f16x8*)&Pm[prow + ks*32 + quad*8];
      #pragma unroll
      for (int t = 0; t < 4; t++) {
        f16x8 vb = *(const f16x8*)&Vt[(t*16 + l15)*264 + ks*32 + quad*8];
        O[t] = __builtin_amdgcn_mfma_f32_16x16x32_f16(pa, vb, O[t], 0, 0, 0);
      }
    }
  }

  #pragma unroll
  for (int r = 0; r < 4; r++) {
    int qlocal = w*16 + quad*4 + r;
    float inv = linv[qlocal];
    int orow = b*4096 + n*256 + qb*64 + qlocal;
    #pragma unroll
    for (int t = 0; t < 4; t++) {
      float o = O[t][r] * inv;
      _Float16 oh = (_Float16)o;
      _Float16 ol = (_Float16)((o - (float)oh) * 2048.f);
      size_t oo = (size_t)orow*1024 + h*64 + t*16 + l15;
      Oh[oo] = oh; Ol[oo] = ol;
    }
  }
}

// ---------------- fused LN2 + gating: one pass over h ----------------
__global__ __launch_bounds__(256) void ln2_gating(
    const float* __restrict__ h,
    const float* __restrict__ g2, const float* __restrict__ b2,
    const float* __restrict__ Wg, const float* __restrict__ bg,
    short* __restrict__ hln,
    int* __restrict__ e1e2, float2* __restrict__ p12, float* __restrict__ entArr) {
  int tid = threadIdx.x, lane = tid & 63, wid = tid >> 6;
  int tok = blockIdx.x*4 + wid;
  const float* row = h + (size_t)tok * 1024;
  float4 xv4[4];
  float s = 0.f, s2 = 0.f;
  #pragma unroll
  for (int q = 0; q < 4; q++) {
    float4 xv = ((const float4*)row)[lane*4 + q];
    xv4[q] = xv;
    s  += xv.x + xv.y + xv.z + xv.w;
    s2 += xv.x*xv.x + xv.y*xv.y + xv.z*xv.z + xv.w*xv.w;
  }
  s = wave_sum64(s); s2 = wave_sum64(s2);
  float mu = s * (1.f/1024.f);
  float var = s2 * (1.f/1024.f) - mu*mu;
  float rs = rsqrtf(var + 1e-5f);
  double mud = (double)mu, rsd = (double)rs;
  double acc[8] = {};
  short* hrow = hln + (size_t)tok * 1024;
  #pragma unroll
  for (int q = 0; q < 4; q++) {
    float4 xv = xv4[q];
    float4 gv = ((const float4*)g2)[lane*4 + q];
    float4 bv = ((const float4*)b2)[lane*4 + q];
    float xs[4] = {xv.x, xv.y, xv.z, xv.w};
    float gs[4] = {gv.x, gv.y, gv.z, gv.w};
    float bs[4] = {bv.x, bv.y, bv.z, bv.w};
    short os[4];
    #pragma unroll
    for (int j = 0; j < 4; j++) {
      int i = lane*16 + q*4 + j;
      os[j] = f2bf((xs[j] - mu) * rs * gs[j] + bs[j]);
      double xn = ((double)xs[j] - mud) * rsd * (double)gs[j] + (double)bs[j];
      const float4 w0 = *(const float4*)&Wg[(size_t)i*8];
      const float4 w1 = *(const float4*)&Wg[(size_t)i*8 + 4];
      acc[0] += xn*(double)w0.x; acc[1] += xn*(double)w0.y;
      acc[2] += xn*(double)w0.z; acc[3] += xn*(double)w0.w;
      acc[4] += xn*(double)w1.x; acc[5] += xn*(double)w1.y;
      acc[6] += xn*(double)w1.z; acc[7] += xn*(double)w1.w;
    }
    short4 o = make_short4(os[0], os[1], os[2], os[3]);
    ((short4*)hrow)[lane*4 + q] = o;
  }
  #pragma unroll
  for (int e = 0; e < 8; e++) acc[e] = wave_sum64d(acc[e]) + (double)bg[e];
  int e1 = 0;
  #pragma unroll
  for (int e = 1; e < 8; e++) if (acc[e] > acc[e1]) e1 = e;
  int e2 = (e1 == 0) ? 1 : 0;
  #pragma unroll
  for (int e = 0; e < 8; e++) if (e != e1 && acc[e] > acc[e2]) e2 = e;
  float lf[8];
  #pragma unroll
  for (int e = 0; e < 8; e++) lf[e] = (float)acc[e];
  float mx = lf[0];
  #pragma unroll
  for (int e = 1; e < 8; e++) mx = fmaxf(mx, lf[e]);
  float ex[8], Z = 0.f;
  #pragma unroll
  for (int e = 0; e < 8; e++) { ex[e] = __expf(lf[e] - mx); Z += ex[e]; }
  float invZ = 1.f / Z, ent = 0.f;
  float p[8];
  #pragma unroll
  for (int e = 0; e < 8; e++) { p[e] = ex[e]*invZ; ent -= p[e]*__logf(p[e] + 1e-8f); }
  if (lane == 0) {
    e1e2[tok] = e1 | (e2 << 8);
    p12[tok]  = make_float2(p[e1], p[e2]);
    entArr[tok] = ent;
  }
}

// ---------------- gating phase 2: LDS-aggregated scatter ----------------
__global__ __launch_bounds__(128) void scatter_kernel(
    const int* __restrict__ e1e2, const float2* __restrict__ p12,
    int* __restrict__ cnt, int* __restrict__ bucket, float* __restrict__ bucketP,
    int* __restrict__ bucketS) {
  __shared__ int lcnt[8], base[8];
  int tid = threadIdx.x;
  if (tid < 8) lcnt[tid] = 0;
  __syncthreads();
  int tok = blockIdx.x*128 + tid;
  int ee = e1e2[tok];
  int e1 = ee & 255, e2 = ee >> 8;
  float2 p = p12[tok];
  int o1 = atomicAdd(&lcnt[e1], 1);
  int o2 = atomicAdd(&lcnt[e2], 1);
  __syncthreads();
  if (tid < 8) base[tid] = atomicAdd(&cnt[tid], lcnt[tid]);
  __syncthreads();
  int i1 = base[e1] + o1;
  bucket[e1*8192 + i1] = tok; bucketP[e1*8192 + i1] = p.x; bucketS[e1*8192 + i1] = 0;
  int i2 = base[e2] + o2;
  bucket[e2*8192 + i2] = tok; bucketP[e2*8192 + i2] = p.y; bucketS[e2*8192 + i2] = 1;
}

__global__ __launch_bounds__(256) void aux_kernel(const float* __restrict__ entArr,
    const int* __restrict__ cnt, float* __restrict__ auxOut) {
  int tid = threadIdx.x;
  float s = 0.f;
  for (int i = tid; i < 8192; i += 256) s += entArr[i];
  s = wave_sum64(s);
  __shared__ float pa[4];
  if ((tid & 63) == 0) pa[tid >> 6] = s;
  __syncthreads();
  if (tid == 0) {
    float tot = pa[0]+pa[1]+pa[2]+pa[3];
    float entMean = tot / 8192.f;
    float pen = 0.f;
    for (int e = 0; e < 8; e++) {
      float usage = (float)cnt[e] / (8192.f + 1e-8f);
      pen += fmaxf(usage - 0.4f, 0.f);
    }
    auxOut[0] = 0.05f * entMean + pen;
  }
}

// ---------------- We transpose (fp32 -> bf16, per expert) ----------------
__global__ void transpose_We(const float* __restrict__ We, short* __restrict__ WeT) {
  int e = blockIdx.z;
  __shared__ float tile[32][33];
  int kt = blockIdx.x, nt = blockIdx.y;
  int tx = threadIdx.x, ty = threadIdx.y;
  const float* src = We + (size_t)e * 1048576;
  short* dst = WeT + (size_t)e * 1048576;
  #pragma unroll
  for (int i = 0; i < 4; i++)
    tile[ty + 8*i][tx] = src[(size_t)(kt*32 + ty + 8*i)*1024 + nt*32 + tx];
  __syncthreads();
  #pragma unroll
  for (int i = 0; i < 4; i++)
    dst[(size_t)(nt*32 + ty + 8*i)*1024 + kt*32 + tx] = f2bf(tile[tx][ty + 8*i]);
}

// ---------------- bf16 MFMA grouped MoE GEMM (128x256 tile, BK=32 dbuf, grid-stride, counted vmcnt) ----------------
// Epilogue writes f16 slots (halves combine traffic). T5 setprio around compute phase.
__global__ __launch_bounds__(256, 2) void moe_gemm(
    const short* __restrict__ hln, const short* __restrict__ WeT,
    const float* __restrict__ be, const int* __restrict__ cnt,
    const int* __restrict__ bucket, const float* __restrict__ bucketP,
    const int* __restrict__ bucketS,
    _Float16* __restrict__ slot0, _Float16* __restrict__ slot1) {
  int e = blockIdx.z;
  int count = cnt[e];
  int n0 = blockIdx.y * 256;
  __shared__ short As[2][4096];   // [128][32] swizzled bf16
  __shared__ short Bs[2][8192];   // [256][32] swizzled bf16
  __shared__ int   toks[128];
  __shared__ float pws[128];
  __shared__ int   sls[128];
  int tid = threadIdx.x;
  int lane = tid & 63, w = tid >> 6;
  int wm = (w & 1) * 64, wn = (w >> 1) * 128;
  int l15 = lane & 15, quad = lane >> 4;
  const short* Bt = WeT + (size_t)e * 1048576;

  // A staging: 512 chunks (2/thread); B staging: 1024 chunks (4/thread).
  int PA0 = tid, PA1 = tid + 256;
  int cA0 = (PA0 & 3) ^ ((PA0 >> 3) & 3);
  int cA1 = (PA1 & 3) ^ ((PA1 >> 3) & 3);
  int PB[4]; size_t gB[4];
  #pragma unroll
  for (int j = 0; j < 4; j++) {
    PB[j] = tid + 256*j;
    int cb = (PB[j] & 3) ^ ((PB[j] >> 3) & 3);
    gB[j] = (size_t)(n0 + (PB[j] >> 2)) * 1024 + cb * 8;
  }

  for (int mtile = blockIdx.x; mtile * 128 < count; mtile += 16) {
    __syncthreads();   // guard toks/LDS reuse across mtile iterations
    if (tid < 128) {
      int idx = mtile*128 + tid;
      int ic = idx < count ? idx : count - 1;
      toks[tid] = bucket[e*8192 + ic];
      pws[tid]  = bucketP[e*8192 + ic];
      sls[tid]  = bucketS[e*8192 + ic];
    }
    __syncthreads();

    size_t gA0 = (size_t)toks[PA0 >> 2] * 1024 + cA0 * 8;
    size_t gA1 = (size_t)toks[PA1 >> 2] * 1024 + cA1 * 8;

    f32x4 acc[4][8] = {};

    // prologue: stage K-slice 0 into buffer 0 (6 loads/thread)
    gld16(hln + gA0, &As[0][PA0*8]);
    gld16(hln + gA1, &As[0][PA1*8]);
    #pragma unroll
    for (int j = 0; j < 4; j++) gld16(Bt + gB[j], &Bs[0][PB[j]*8]);

    int cur = 0;
    for (int it = 0; it < 32; ++it) {
      if (it < 31) {
        int kb = (it + 1) * 32;
        int nb = cur ^ 1;
        gld16(hln + gA0 + kb, &As[nb][PA0*8]);
        gld16(hln + gA1 + kb, &As[nb][PA1*8]);
        #pragma unroll
        for (int j = 0; j < 4; j++) gld16(Bt + gB[j] + kb, &Bs[nb][PB[j]*8]);
        asm volatile("s_waitcnt vmcnt(6)" ::: "memory");  // loads(it) done; loads(it+1) fly
      } else {
        asm volatile("s_waitcnt vmcnt(0)" ::: "memory");
      }
      __builtin_amdgcn_s_barrier();
      __builtin_amdgcn_sched_barrier(0);
      __builtin_amdgcn_s_setprio(1);
      bf16x8 bfr[8];
      #pragma unroll
      for (int nt = 0; nt < 8; nt++) {
        int row = wn + nt*16 + l15;
        int pc = quad ^ ((row >> 1) & 3);
        bfr[nt] = *(const bf16x8*)&Bs[cur][row*32 + pc*8];
      }
      #pragma unroll
      for (int mt = 0; mt < 4; mt++) {
        int row = wm + mt*16 + l15;
        int pc = quad ^ ((row >> 1) & 3);
        bf16x8 af = *(const bf16x8*)&As[cur][row*32 + pc*8];
        #pragma unroll
        for (int nt = 0; nt < 8; nt++)
          acc[mt][nt] = __builtin_amdgcn_mfma_f32_16x16x32_bf16(af, bfr[nt], acc[mt][nt], 0, 0, 0);
      }
      __builtin_amdgcn_s_setprio(0);
      asm volatile("s_waitcnt lgkmcnt(0)" ::: "memory");
      __builtin_amdgcn_sched_barrier(0);
      __builtin_amdgcn_s_barrier();
      cur ^= 1;
    }

    #pragma unroll
    for (int mt = 0; mt < 4; mt++) {
      #pragma unroll
      for (int r = 0; r < 4; r++) {
        int m = wm + mt*16 + quad*4 + r;
        if (mtile*128 + m < count) {
          int tok = toks[m];
          float pp = pws[m];
          _Float16* dst = sls[m] ? slot1 : slot0;
          #pragma unroll
          for (int nt = 0; nt < 8; nt++) {
            int col = n0 + wn + nt*16 + l15;
            dst[(size_t)tok*1024 + col] = (_Float16)(pp * (acc[mt][nt][r] + be[e*1024 + col]));
          }
        }
      }
    }
  }
}

// ---------------- final combine (f16 slots) ----------------
__global__ __launch_bounds__(256) void final_add(float* __restrict__ out,
    const _Float16* __restrict__ s0, const _Float16* __restrict__ s1) {
  const int total = 8388608 / 8;   // per 8 elements
  for (int i = blockIdx.x*256 + threadIdx.x; i < total; i += gridDim.x*256) {
    f16x8 a0 = ((const f16x8*)s0)[i];
    f16x8 a1 = ((const f16x8*)s1)[i];
    float4 o0 = ((float4*)out)[2*i];
    float4 o1 = ((float4*)out)[2*i + 1];
    o0.x += (float)a0[0] + (float)a1[0]; o0.y += (float)a0[1] + (float)a1[1];
    o0.z += (float)a0[2] + (float)a1[2]; o0.w += (float)a0[3] + (float)a1[3];
    o1.x += (float)a0[4] + (float)a1[4]; o1.y += (float)a0[5] + (float)a1[5];
    o1.z += (float)a0[6] + (float)a1[6]; o1.w += (float)a0[7] + (float)a1[7];
    ((float4*)out)[2*i] = o0;
    ((float4*)out)[2*i + 1] = o1;
  }
}

// ---------------- host launcher ----------------
extern "C" void kernel_launch(void* const* d_in, const int* in_sizes, int n_in,
                              void* d_out, int out_size, void* d_ws, size_t ws_size,
                              hipStream_t stream) {
  const float* x    = (const float*)d_in[0];
  const float* Wq   = (const float*)d_in[1];
  const float* bq   = (const float*)d_in[2];
  const float* Wk   = (const float*)d_in[3];
  const float* bk   = (const float*)d_in[4];
  const float* Wv   = (const float*)d_in[5];
  const float* bv   = (const float*)d_in[6];
  const float* Wo   = (const float*)d_in[7];
  const float* bo   = (const float*)d_in[8];
  const float* ln1g = (const float*)d_in[9];
  const float* ln1b = (const float*)d_in[10];
  const float* ln2g = (const float*)d_in[11];
  const float* ln2b = (const float*)d_in[12];
  const float* Wg   = (const float*)d_in[13];
  const float* bg   = (const float*)d_in[14];
  const float* We   = (const float*)d_in[15];
  const float* be   = (const float*)d_in[16];
  float* out = (float*)d_out;

  char* ws = (char*)d_ws;
  size_t off = 0;
  auto alloc = [&](size_t bytes) { char* p = ws + off; off += (bytes + 255) & ~(size_t)255; return p; };
  _Float16* xh  = (_Float16*)alloc(16777216);  // 8192x1024 f16 (LN1 hi); reused as Oh
  _Float16* xl  = (_Float16*)alloc(16777216);  // (LN1 lo*2048); reused as Ol
  float* Qs    = (float*)alloc(33554432);      // 8192x1024 f32; reused as hln
  float* Kf    = (float*)alloc(4194304);
  float* Vf    = (float*)alloc(4194304);
  short* WeT   = (short*)alloc(16777216);
  float* slot0 = (float*)alloc(33554432);      // f16 use: 16MB; front also WoT scratch
  float* slot1 = (float*)alloc(33554432);      // f16 use: 16MB; front also BTqkv scratch
  int*   bucket  = (int*)alloc(262144);
  float* bucketP = (float*)alloc(262144);
  int*   bucketS = (int*)alloc(262144);
  int*   cnt     = (int*)alloc(256);
  float* entArr  = (float*)alloc(32768);
  int*   e1e2    = (int*)alloc(32768);
  float2* p12    = (float2*)alloc(65536);
  _Float16* Oh = xh;            // alias: xh/xl dead after QKV GEMM
  _Float16* Ol = xl;
  short* hln   = (short*)Qs;    // alias: Qs dead after attention
  _Float16* WoTh    = (_Float16*)slot0;
  _Float16* WoTl    = (_Float16*)(slot0 + 524288);
  _Float16* BTqkv_h = (_Float16*)slot1;
  _Float16* BTqkv_l = (_Float16*)((char*)slot1 + 2621440);

  hipMemsetAsync(cnt, 0, 256, stream);
  t_w_f16<<<dim3(32, 32), dim3(32, 8), 0, stream>>>(Wq, 1024, BTqkv_h, BTqkv_l, 0);
  t_w_f16<<<dim3(32, 4),  dim3(32, 8), 0, stream>>>(Wk, 128,  BTqkv_h, BTqkv_l, 1024);
  t_w_f16<<<dim3(32, 4),  dim3(32, 8), 0, stream>>>(Wv, 128,  BTqkv_h, BTqkv_l, 1152);
  t_w_f16<<<dim3(32, 32), dim3(32, 8), 0, stream>>>(Wo, 1024, WoTh, WoTl, 0);
  transpose_We<<<dim3(32,32,8), dim3(32,8), 0, stream>>>(We, WeT);

  ln_split<<<8192, 256, 0, stream>>>(x, ln1g, ln1b, xh, xl);
  gemm_dma<0><<<dim3(64,10), 256, 0, stream>>>(xh, xl, BTqkv_h, BTqkv_l, bq, bk, bv,
                                               nullptr, Qs, Kf, Vf);
  attn_mfma<<<dim3(4,16,32), 256, 0, stream>>>(Qs, Kf, Vf, Oh, Ol);
  gemm_dma<1><<<dim3(64,8), 256, 0, stream>>>(Oh, Ol, WoTh, WoTl, bo, nullptr, nullptr,
                                              x, out, nullptr, nullptr);
  ln2_gating<<<2048, 256, 0, stream>>>(out, ln2g, ln2b, Wg, bg, hln, e1e2, p12, entArr);
  scatter_kernel<<<64, 128, 0, stream>>>(e1e2, p12, cnt, bucket, bucketP, bucketS);
  aux_kernel<<<1, 256, 0, stream>>>(entArr, cnt, out + 8388608);
  moe_gemm<<<dim3(16,4,8), 256, 0, stream>>>(hln, WeT, be, cnt, bucket, bucketP, bucketS,
                                             (_Float16*)slot0, (_Float16*)slot1);
  final_add<<<2048, 256, 0, stream>>>(out, (const _Float16*)slot0, (const _Float16*)slot1);
}

// Round 15
// 497.608 us; speedup vs baseline: 1.0765x; 1.0120x over previous
//
#include <hip/hip_runtime.h>
#include <hip/hip_bf16.h>
#include <stdint.h>

// ---------------- types / helpers ----------------
typedef __attribute__((ext_vector_type(8))) short bf16x8;
typedef __attribute__((ext_vector_type(8))) _Float16 f16x8;
typedef __attribute__((ext_vector_type(4))) _Float16 f16x4;
typedef __attribute__((ext_vector_type(4))) float f32x4;

__device__ __forceinline__ short f2bf(float f) {
  __hip_bfloat16 h = __float2bfloat16(f);
  union { __hip_bfloat16 h; short s; } u; u.h = h; return u.s;
}

__device__ __forceinline__ unsigned pk2(float a, float b) {
  union { _Float16 h; unsigned short s; } ua, ub;
  ua.h = (_Float16)a; ub.h = (_Float16)b;
  return (unsigned)ua.s | ((unsigned)ub.s << 16);
}

// async global->LDS, 16B per lane. LDS dest must be wave-uniform base + lane*16.
__device__ __forceinline__ void gld16(const void* g, void* l) {
  __builtin_amdgcn_global_load_lds((const __attribute__((address_space(1))) void*)g,
                                   (__attribute__((address_space(3))) void*)l, 16, 0, 0);
}

__device__ __forceinline__ float wave_sum64(float v) {
  #pragma unroll
  for (int off = 1; off < 64; off <<= 1) v += __shfl_xor(v, off);
  return v;
}
__device__ __forceinline__ double wave_sum64d(double v) {
  #pragma unroll
  for (int off = 1; off < 64; off <<= 1) v += __shfl_xor(v, off);
  return v;
}

// ---------------- fused prologue: We transpose + 4 weight splits + LN1 ----------------
// All six prologue jobs read only network inputs -> one launch (18688 blocks),
// removing 5 launch gaps and the serial under-utilized small dispatches.
// Block map: [0,8192) transpose_We | [8192,10496) t_w_f16 {Wq,Wk,Wv,Wo} | [10496,18688) ln_split.
__global__ __launch_bounds__(256) void prologue_fused(
    const float* __restrict__ x, const float* __restrict__ ln1g, const float* __restrict__ ln1b,
    const float* __restrict__ Wq, const float* __restrict__ Wk,
    const float* __restrict__ Wv, const float* __restrict__ Wo,
    const float* __restrict__ We,
    _Float16* __restrict__ xh, _Float16* __restrict__ xl,
    _Float16* __restrict__ BTqkv_h, _Float16* __restrict__ BTqkv_l,
    _Float16* __restrict__ WoTh, _Float16* __restrict__ WoTl,
    short* __restrict__ WeT) {
  __shared__ float tile[32][33];
  __shared__ float pa[4], pb[4];
  int b = blockIdx.x;
  int tid = threadIdx.x;

  if (b < 8192) {
    // ---- transpose_We (fp32 -> bf16, per expert) ----
    int e = b >> 10, rem = b & 1023;
    int kt = rem & 31, nt = rem >> 5;
    int tx = tid & 31, ty = tid >> 5;
    const float* src = We + (size_t)e * 1048576;
    short* dst = WeT + (size_t)e * 1048576;
    #pragma unroll
    for (int i = 0; i < 4; i++)
      tile[ty + 8*i][tx] = src[(size_t)(kt*32 + ty + 8*i)*1024 + nt*32 + tx];
    __syncthreads();
    #pragma unroll
    for (int i = 0; i < 4; i++)
      dst[(size_t)(nt*32 + ty + 8*i)*1024 + kt*32 + tx] = f2bf(tile[tx][ty + 8*i]);
  } else if (b < 10496) {
    // ---- weight transpose + fp16 hi/lo split ----
    int bb = b - 8192;
    const float* src; int srcN, kt, nt, row0;
    _Float16 *dh, *dl;
    if (bb < 1024)      { src = Wq; srcN = 1024; kt = bb & 31; nt = bb >> 5; row0 = 0;    dh = BTqkv_h; dl = BTqkv_l; }
    else if (bb < 1152) { int c = bb - 1024; src = Wk; srcN = 128; kt = c & 31; nt = c >> 5; row0 = 1024; dh = BTqkv_h; dl = BTqkv_l; }
    else if (bb < 1280) { int c = bb - 1152; src = Wv; srcN = 128; kt = c & 31; nt = c >> 5; row0 = 1152; dh = BTqkv_h; dl = BTqkv_l; }
    else                { int c = bb - 1280; src = Wo; srcN = 1024; kt = c & 31; nt = c >> 5; row0 = 0;   dh = WoTh;    dl = WoTl; }
    int tx = tid & 31, ty = tid >> 5;
    #pragma unroll
    for (int i = 0; i < 4; i++)
      tile[ty + 8*i][tx] = src[(size_t)(kt*32 + ty + 8*i)*srcN + nt*32 + tx];
    __syncthreads();
    #pragma unroll
    for (int i = 0; i < 4; i++) {
      float v = tile[tx][ty + 8*i];
      _Float16 h = (_Float16)v;
      _Float16 l = (_Float16)((v - (float)h) * 2048.0f);
      size_t o = (size_t)(row0 + nt*32 + ty + 8*i)*1024 + kt*32 + tx;
      dh[o] = h; dl[o] = l;
    }
  } else {
    // ---- LN1: emits split-f16 (hi, lo*2048) ----
    int t = b - 10496;
    const float4 v = ((const float4*)(x + (size_t)t * 1024))[tid];
    float s = v.x + v.y + v.z + v.w;
    float s2 = v.x*v.x + v.y*v.y + v.z*v.z + v.w*v.w;
    s = wave_sum64(s); s2 = wave_sum64(s2);
    int wid = tid >> 6, lane = tid & 63;
    if (lane == 0) { pa[wid] = s; pb[wid] = s2; }
    __syncthreads();
    float S = pa[0]+pa[1]+pa[2]+pa[3], S2 = pb[0]+pb[1]+pb[2]+pb[3];
    float mu = S * (1.f/1024.f);
    float var = S2 * (1.f/1024.f) - mu*mu;
    float rs = rsqrtf(var + 1e-5f);
    const float4 gv = ((const float4*)ln1g)[tid];
    const float4 bv = ((const float4*)ln1b)[tid];
    float4 o;
    o.x = (v.x-mu)*rs*gv.x + bv.x; o.y = (v.y-mu)*rs*gv.y + bv.y;
    o.z = (v.z-mu)*rs*gv.z + bv.z; o.w = (v.w-mu)*rs*gv.w + bv.w;
    f16x4 hv, lv;
    hv.x = (_Float16)o.x; lv.x = (_Float16)((o.x - (float)hv.x)*2048.f);
    hv.y = (_Float16)o.y; lv.y = (_Float16)((o.y - (float)hv.y)*2048.f);
    hv.z = (_Float16)o.z; lv.z = (_Float16)((o.z - (float)hv.z)*2048.f);
    hv.w = (_Float16)o.w; lv.w = (_Float16)((o.w - (float)hv.w)*2048.f);
    *(f16x4*)&xh[(size_t)t*1024 + tid*4] = hv;
    *(f16x4*)&xl[(size_t)t*1024 + tid*4] = lv;
  }
}

// ---------------- split-fp16 DMA MFMA GEMM (128x128, BK=32, dbuf, counted-vmcnt) ----------------
// r13 lesson (XCD model): workgroups round-robin XCDs by linear id; same-A-panel
// blocks in the x=mtile-fastest layout are spaced 64 (== 0 mod 8) -> SAME XCD L2,
// A fetched once per XCD (53MB). Keep x = m-tile fastest (r11 config, best: ~91us).
// T4 counted vmcnt(8); T5 setprio; swizzle cp = c ^ ((row>>1)&3) (0 conflicts, r5).
template<int MODE>
__global__ __launch_bounds__(256, 2) void gemm_dma(
    const _Float16* __restrict__ Agh, const _Float16* __restrict__ Agl,
    const _Float16* __restrict__ BTh, const _Float16* __restrict__ BTl,
    const float* __restrict__ b0, const float* __restrict__ b1, const float* __restrict__ b2,
    const float* __restrict__ resid,
    float* __restrict__ out0, float* __restrict__ out1, float* __restrict__ out2) {
  int m0 = blockIdx.x * 128;
  int y = blockIdx.y;
  int n0 = y * 128;
  float* dst; const float* biasp; int dcol0, ld;
  if (MODE == 0) {
    if (y < 8)      { dst = out0; biasp = b0 + y*128; dcol0 = y*128; ld = 1024; }
    else if (y == 8){ dst = out1; biasp = b1; dcol0 = 0; ld = 128; }
    else            { dst = out2; biasp = b2; dcol0 = 0; ld = 128; }
  } else            { dst = out0; biasp = b0 + y*128; dcol0 = y*128; ld = 1024; }

  __shared__ _Float16 AhS[2][4096];   // [128][32] swizzled
  __shared__ _Float16 AlS[2][4096];
  __shared__ _Float16 BhS[2][4096];   // [128][32] swizzled
  __shared__ _Float16 BlS[2][4096];
  int tid = threadIdx.x;
  int lane = tid & 63, w = tid >> 6;
  int wm = (w & 1) * 64, wn = (w >> 1) * 64;
  int l15 = lane & 15, quad = lane >> 4;

  // Staging geometry (fixed across K): 2 chunks/thread per array (512 chunks each).
  int P0 = tid, P1 = tid + 256;
  int c0 = (P0 & 3) ^ ((P0 >> 3) & 3);
  int c1 = (P1 & 3) ^ ((P1 >> 3) & 3);
  size_t gA0 = (size_t)(m0 + (P0 >> 2)) * 1024 + c0 * 8;
  size_t gA1 = (size_t)(m0 + (P1 >> 2)) * 1024 + c1 * 8;
  size_t gB0 = (size_t)(n0 + (P0 >> 2)) * 1024 + c0 * 8;
  size_t gB1 = (size_t)(n0 + (P1 >> 2)) * 1024 + c1 * 8;

  f32x4 accM[4][4] = {};
  f32x4 accC[4][4] = {};

  // prologue: stage K-tile 0 into buffer 0 (8 loads/thread)
  gld16(Agh + gA0, &AhS[0][P0*8]);
  gld16(Agh + gA1, &AhS[0][P1*8]);
  gld16(Agl + gA0, &AlS[0][P0*8]);
  gld16(Agl + gA1, &AlS[0][P1*8]);
  gld16(BTh + gB0, &BhS[0][P0*8]);
  gld16(BTh + gB1, &BhS[0][P1*8]);
  gld16(BTl + gB0, &BlS[0][P0*8]);
  gld16(BTl + gB1, &BlS[0][P1*8]);

  int cur = 0;
  for (int it = 0; it < 32; ++it) {
    if (it < 31) {
      int kb = (it + 1) * 32;
      int nb = cur ^ 1;
      gld16(Agh + gA0 + kb, &AhS[nb][P0*8]);
      gld16(Agh + gA1 + kb, &AhS[nb][P1*8]);
      gld16(Agl + gA0 + kb, &AlS[nb][P0*8]);
      gld16(Agl + gA1 + kb, &AlS[nb][P1*8]);
      gld16(BTh + gB0 + kb, &BhS[nb][P0*8]);
      gld16(BTh + gB1 + kb, &BhS[nb][P1*8]);
      gld16(BTl + gB0 + kb, &BlS[nb][P0*8]);
      gld16(BTl + gB1 + kb, &BlS[nb][P1*8]);
      asm volatile("s_waitcnt vmcnt(8)" ::: "memory");   // loads(it) done; loads(it+1) fly
    } else {
      asm volatile("s_waitcnt vmcnt(0)" ::: "memory");
    }
    __builtin_amdgcn_s_barrier();
    __builtin_amdgcn_sched_barrier(0);
    __builtin_amdgcn_s_setprio(1);
    f16x8 bh[4], bl[4];
    #pragma unroll
    for (int nt = 0; nt < 4; nt++) {
      int row = wn + nt*16 + l15;
      int pc = quad ^ ((row >> 1) & 3);
      bh[nt] = *(const f16x8*)&BhS[cur][row*32 + pc*8];
      bl[nt] = *(const f16x8*)&BlS[cur][row*32 + pc*8];
    }
    #pragma unroll
    for (int mt = 0; mt < 4; mt++) {
      int row = wm + mt*16 + l15;
      int pc = quad ^ ((row >> 1) & 3);
      f16x8 ah = *(const f16x8*)&AhS[cur][row*32 + pc*8];
      f16x8 al = *(const f16x8*)&AlS[cur][row*32 + pc*8];
      #pragma unroll
      for (int nt = 0; nt < 4; nt++) {
        accM[mt][nt] = __builtin_amdgcn_mfma_f32_16x16x32_f16(ah, bh[nt], accM[mt][nt], 0, 0, 0);
        accC[mt][nt] = __builtin_amdgcn_mfma_f32_16x16x32_f16(ah, bl[nt], accC[mt][nt], 0, 0, 0);
        accC[mt][nt] = __builtin_amdgcn_mfma_f32_16x16x32_f16(al, bh[nt], accC[mt][nt], 0, 0, 0);
      }
    }
    __builtin_amdgcn_s_setprio(0);
    asm volatile("s_waitcnt lgkmcnt(0)" ::: "memory");   // own ds_reads landed
    __builtin_amdgcn_sched_barrier(0);
    __builtin_amdgcn_s_barrier();                        // buf[cur] free for reuse
    cur ^= 1;
  }

  const float inv2048 = 1.0f / 2048.0f;
  #pragma unroll
  for (int mt = 0; mt < 4; mt++)
    #pragma unroll
    for (int r = 0; r < 4; r++) {
      int row = m0 + wm + mt*16 + quad*4 + r;
      #pragma unroll
      for (int nt = 0; nt < 4; nt++) {
        int c = wn + nt*16 + l15;
        float v = accM[mt][nt][r] + accC[mt][nt][r]*inv2048 + biasp[c];
        if (MODE == 1) v += resid[(size_t)row*1024 + dcol0 + c];
        dst[(size_t)row*ld + dcol0 + c] = v;
      }
    }
}

// ---------------- MFMA windowed attention ----------------
// Epilogue writes split-f16 (hi, lo*2048) for the Wo DMA GEMM.
__global__ __launch_bounds__(256, 2) void attn_mfma(
    const float* __restrict__ Qs, const float* __restrict__ Kf, const float* __restrict__ Vf,
    _Float16* __restrict__ Oh, _Float16* __restrict__ Ol) {
  int qb = blockIdx.x, n = blockIdx.y;
  int b = blockIdx.z >> 4, h = blockIdx.z & 15;
  int g = h & 1;
  int tid = threadIdx.x;
  int lane = tid & 63, w = tid >> 6;
  int l15 = lane & 15, quad = lane >> 4;

  __shared__ __align__(16) char smem[70912];
  _Float16* Vt = (_Float16*)smem;                 // [64][264]
  _Float16* Qh = (_Float16*)(smem + 33792);       // [64][72]
  _Float16* Ql = (_Float16*)(smem + 43008);
  _Float16* Kh = (_Float16*)(smem + 52224);
  _Float16* Kl = (_Float16*)(smem + 61440);
  _Float16* Pm = (_Float16*)(smem + 33792);       // alias over Q/K
  float*   linv = (float*)(smem + 70656);

  int qtok0 = b*4096 + n*128 + qb*64;
  int key0  = b*4096 + n*128;

  #pragma unroll
  for (int i = 0; i < 4; i++) {
    int idx = tid + 256*i;
    int row = idx >> 4, c4 = idx & 15;
    float4 v = *(const float4*)&Qs[(size_t)(qtok0+row)*1024 + h*64 + c4*4];
    f16x4 hv, lv;
    hv.x = (_Float16)v.x; lv.x = (_Float16)(v.x - (float)hv.x);
    hv.y = (_Float16)v.y; lv.y = (_Float16)(v.y - (float)hv.y);
    hv.z = (_Float16)v.z; lv.z = (_Float16)(v.z - (float)hv.z);
    hv.w = (_Float16)v.w; lv.w = (_Float16)(v.w - (float)hv.w);
    *(f16x4*)&Qh[row*72 + c4*4] = hv;
    *(f16x4*)&Ql[row*72 + c4*4] = lv;
  }
  {
    int kk = tid >> 4, dd = tid & 15;
    #pragma unroll
    for (int i = 0; i < 8; i++) {
      int p = i*16 + kk;
      float4 v0 = *(const float4*)&Vf[(size_t)(key0 + 2*p    )*128 + g*64 + dd*4];
      float4 v1 = *(const float4*)&Vf[(size_t)(key0 + 2*p + 1)*128 + g*64 + dd*4];
      *(unsigned*)&Vt[(dd*4+0)*264 + 2*p] = pk2(v0.x, v1.x);
      *(unsigned*)&Vt[(dd*4+1)*264 + 2*p] = pk2(v0.y, v1.y);
      *(unsigned*)&Vt[(dd*4+2)*264 + 2*p] = pk2(v0.z, v1.z);
      *(unsigned*)&Vt[(dd*4+3)*264 + 2*p] = pk2(v0.w, v1.w);
    }
  }
  __syncthreads();

  f16x8 qh[2], ql[2];
  {
    int qrow = (w*16 + l15)*72;
    qh[0] = *(const f16x8*)&Qh[qrow + quad*8];
    qh[1] = *(const f16x8*)&Qh[qrow + 32 + quad*8];
    ql[0] = *(const f16x8*)&Ql[qrow + quad*8];
    ql[1] = *(const f16x8*)&Ql[qrow + 32 + quad*8];
  }

  f32x4 S[16];
  #pragma unroll
  for (int t = 0; t < 16; t++) S[t] = (f32x4){0.f,0.f,0.f,0.f};

  for (int c = 0; c < 4; c++) {
    if (c) __syncthreads();
    #pragma unroll
    for (int i = 0; i < 4; i++) {
      int idx = tid + 256*i;
      int row = idx >> 4, c4 = idx & 15;
      float4 v = *(const float4*)&Kf[(size_t)(key0 + c*64 + row)*128 + g*64 + c4*4];
      f16x4 hv, lv;
      hv.x = (_Float16)v.x; lv.x = (_Float16)(v.x - (float)hv.x);
      hv.y = (_Float16)v.y; lv.y = (_Float16)(v.y - (float)hv.y);
      hv.z = (_Float16)v.z; lv.z = (_Float16)(v.z - (float)hv.z);
      hv.w = (_Float16)v.w; lv.w = (_Float16)(v.w - (float)hv.w);
      *(f16x4*)&Kh[row*72 + c4*4] = hv;
      *(f16x4*)&Kl[row*72 + c4*4] = lv;
    }
    __syncthreads();
    #pragma unroll
    for (int t = 0; t < 4; t++) {
      int krow = (t*16 + l15)*72;
      f16x8 kh0 = *(const f16x8*)&Kh[krow + quad*8];
      f16x8 kh1 = *(const f16x8*)&Kh[krow + 32 + quad*8];
      f16x8 kl0 = *(const f16x8*)&Kl[krow + quad*8];
      f16x8 kl1 = *(const f16x8*)&Kl[krow + 32 + quad*8];
      int ti = c*4 + t;
      S[ti] = __builtin_amdgcn_mfma_f32_16x16x32_f16(qh[0], kh0, S[ti], 0, 0, 0);
      S[ti] = __builtin_amdgcn_mfma_f32_16x16x32_f16(ql[0], kh0, S[ti], 0, 0, 0);
      S[ti] = __builtin_amdgcn_mfma_f32_16x16x32_f16(qh[0], kl0, S[ti], 0, 0, 0);
      S[ti] = __builtin_amdgcn_mfma_f32_16x16x32_f16(qh[1], kh1, S[ti], 0, 0, 0);
      S[ti] = __builtin_amdgcn_mfma_f32_16x16x32_f16(ql[1], kh1, S[ti], 0, 0, 0);
      S[ti] = __builtin_amdgcn_mfma_f32_16x16x32_f16(qh[1], kl1, S[ti], 0, 0, 0);
    }
  }

  float lrow[4];
  #pragma unroll
  for (int r = 0; r < 4; r++) {
    float mx = S[0][r];
    #pragma unroll
    for (int t = 1; t < 16; t++) mx = fmaxf(mx, S[t][r]);
    mx = fmaxf(mx, __shfl_xor(mx, 1)); mx = fmaxf(mx, __shfl_xor(mx, 2));
    mx = fmaxf(mx, __shfl_xor(mx, 4)); mx = fmaxf(mx, __shfl_xor(mx, 8));
    float sum = 0.f;
    #pragma unroll
    for (int t = 0; t < 16; t++) {
      float e = __expf((S[t][r] - mx) * 0.125f);
      S[t][r] = e; sum += e;
    }
    sum += __shfl_xor(sum, 1); sum += __shfl_xor(sum, 2);
    sum += __shfl_xor(sum, 4); sum += __shfl_xor(sum, 8);
    lrow[r] = sum;
  }
  if (l15 == 0) {
    #pragma unroll
    for (int r = 0; r < 4; r++) linv[w*16 + quad*4 + r] = 1.f / lrow[r];
  }
  __syncthreads();

  #pragma unroll
  for (int r = 0; r < 4; r++) {
    int q = w*16 + quad*4 + r;
    bool mine = (l15 & 1) ? (r >= 2) : (r < 2);
    #pragma unroll
    for (int t = 0; t < 16; t++) {
      float own = S[t][r];
      float oth = __shfl_xor(own, 1);
      if (mine) {
        float e0 = (l15 & 1) ? oth : own;
        float e1 = (l15 & 1) ? own : oth;
        *(unsigned*)&Pm[q*264 + t*16 + (l15 & ~1)] = pk2(e0, e1);
      }
    }
  }
  __syncthreads();

  f32x4 O[4];
  #pragma unroll
  for (int t = 0; t < 4; t++) O[t] = (f32x4){0.f,0.f,0.f,0.f};
  {
    int prow = (w*16 + l15)*264;
    #pragma unroll
    for (int ks = 0; ks < 8; ks++) {
      f16x8 pa = *(const f16x8*)&Pm[prow + ks*32 + quad*8];
      #pragma unroll
      for (int t = 0; t < 4; t++) {
        f16x8 vb = *(const f16x8*)&Vt[(t*16 + l15)*264 + ks*32 + quad*8];
        O[t] = __builtin_amdgcn_mfma_f32_16x16x32_f16(pa, vb, O[t], 0, 0, 0);
      }
    }
  }

  #pragma unroll
  for (int r = 0; r < 4; r++) {
    int qlocal = w*16 + quad*4 + r;
    float inv = linv[qlocal];
    int orow = b*4096 + n*256 + qb*64 + qlocal;
    #pragma unroll
    for (int t = 0; t < 4; t++) {
      float o = O[t][r] * inv;
      _Float16 oh = (_Float16)o;
      _Float16 ol = (_Float16)((o - (float)oh) * 2048.f);
      size_t oo = (size_t)orow*1024 + h*64 + t*16 + l15;
      Oh[oo] = oh; Ol[oo] = ol;
    }
  }
}

// ---------------- fused LN2 + gating: one pass over h ----------------
__global__ __launch_bounds__(256) void ln2_gating(
    const float* __restrict__ h,
    const float* __restrict__ g2, const float* __restrict__ b2,
    const float* __restrict__ Wg, const float* __restrict__ bg,
    short* __restrict__ hln,
    int* __restrict__ e1e2, float2* __restrict__ p12, float* __restrict__ entArr) {
  int tid = threadIdx.x, lane = tid & 63, wid = tid >> 6;
  int tok = blockIdx.x*4 + wid;
  const float* row = h + (size_t)tok * 1024;
  float4 xv4[4];
  float s = 0.f, s2 = 0.f;
  #pragma unroll
  for (int q = 0; q < 4; q++) {
    float4 xv = ((const float4*)row)[lane*4 + q];
    xv4[q] = xv;
    s  += xv.x + xv.y + xv.z + xv.w;
    s2 += xv.x*xv.x + xv.y*xv.y + xv.z*xv.z + xv.w*xv.w;
  }
  s = wave_sum64(s); s2 = wave_sum64(s2);
  float mu = s * (1.f/1024.f);
  float var = s2 * (1.f/1024.f) - mu*mu;
  float rs = rsqrtf(var + 1e-5f);
  double mud = (double)mu, rsd = (double)rs;
  double acc[8] = {};
  short* hrow = hln + (size_t)tok * 1024;
  #pragma unroll
  for (int q = 0; q < 4; q++) {
    float4 xv = xv4[q];
    float4 gv = ((const float4*)g2)[lane*4 + q];
    float4 bv = ((const float4*)b2)[lane*4 + q];
    float xs[4] = {xv.x, xv.y, xv.z, xv.w};
    float gs[4] = {gv.x, gv.y, gv.z, gv.w};
    float bs[4] = {bv.x, bv.y, bv.z, bv.w};
    short os[4];
    #pragma unroll
    for (int j = 0; j < 4; j++) {
      int i = lane*16 + q*4 + j;
      os[j] = f2bf((xs[j] - mu) * rs * gs[j] + bs[j]);
      double xn = ((double)xs[j] - mud) * rsd * (double)gs[j] + (double)bs[j];
      const float4 w0 = *(const float4*)&Wg[(size_t)i*8];
      const float4 w1 = *(const float4*)&Wg[(size_t)i*8 + 4];
      acc[0] += xn*(double)w0.x; acc[1] += xn*(double)w0.y;
      acc[2] += xn*(double)w0.z; acc[3] += xn*(double)w0.w;
      acc[4] += xn*(double)w1.x; acc[5] += xn*(double)w1.y;
      acc[6] += xn*(double)w1.z; acc[7] += xn*(double)w1.w;
    }
    short4 o = make_short4(os[0], os[1], os[2], os[3]);
    ((short4*)hrow)[lane*4 + q] = o;
  }
  #pragma unroll
  for (int e = 0; e < 8; e++) acc[e] = wave_sum64d(acc[e]) + (double)bg[e];
  int e1 = 0;
  #pragma unroll
  for (int e = 1; e < 8; e++) if (acc[e] > acc[e1]) e1 = e;
  int e2 = (e1 == 0) ? 1 : 0;
  #pragma unroll
  for (int e = 0; e < 8; e++) if (e != e1 && acc[e] > acc[e2]) e2 = e;
  float lf[8];
  #pragma unroll
  for (int e = 0; e < 8; e++) lf[e] = (float)acc[e];
  float mx = lf[0];
  #pragma unroll
  for (int e = 1; e < 8; e++) mx = fmaxf(mx, lf[e]);
  float ex[8], Z = 0.f;
  #pragma unroll
  for (int e = 0; e < 8; e++) { ex[e] = __expf(lf[e] - mx); Z += ex[e]; }
  float invZ = 1.f / Z, ent = 0.f;
  float p[8];
  #pragma unroll
  for (int e = 0; e < 8; e++) { p[e] = ex[e]*invZ; ent -= p[e]*__logf(p[e] + 1e-8f); }
  if (lane == 0) {
    e1e2[tok] = e1 | (e2 << 8);
    p12[tok]  = make_float2(p[e1], p[e2]);
    entArr[tok] = ent;
  }
}

// ---------------- gating phase 2: LDS-aggregated scatter ----------------
__global__ __launch_bounds__(128) void scatter_kernel(
    const int* __restrict__ e1e2, const float2* __restrict__ p12,
    int* __restrict__ cnt, int* __restrict__ bucket, float* __restrict__ bucketP,
    int* __restrict__ bucketS) {
  __shared__ int lcnt[8], base[8];
  int tid = threadIdx.x;
  if (tid < 8) lcnt[tid] = 0;
  __syncthreads();
  int tok = blockIdx.x*128 + tid;
  int ee = e1e2[tok];
  int e1 = ee & 255, e2 = ee >> 8;
  float2 p = p12[tok];
  int o1 = atomicAdd(&lcnt[e1], 1);
  int o2 = atomicAdd(&lcnt[e2], 1);
  __syncthreads();
  if (tid < 8) base[tid] = atomicAdd(&cnt[tid], lcnt[tid]);
  __syncthreads();
  int i1 = base[e1] + o1;
  bucket[e1*8192 + i1] = tok; bucketP[e1*8192 + i1] = p.x; bucketS[e1*8192 + i1] = 0;
  int i2 = base[e2] + o2;
  bucket[e2*8192 + i2] = tok; bucketP[e2*8192 + i2] = p.y; bucketS[e2*8192 + i2] = 1;
}

__global__ __launch_bounds__(256) void aux_kernel(const float* __restrict__ entArr,
    const int* __restrict__ cnt, float* __restrict__ auxOut) {
  int tid = threadIdx.x;
  float s = 0.f;
  for (int i = tid; i < 8192; i += 256) s += entArr[i];
  s = wave_sum64(s);
  __shared__ float pa[4];
  if ((tid & 63) == 0) pa[tid >> 6] = s;
  __syncthreads();
  if (tid == 0) {
    float tot = pa[0]+pa[1]+pa[2]+pa[3];
    float entMean = tot / 8192.f;
    float pen = 0.f;
    for (int e = 0; e < 8; e++) {
      float usage = (float)cnt[e] / (8192.f + 1e-8f);
      pen += fmaxf(usage - 0.4f, 0.f);
    }
    auxOut[0] = 0.05f * entMean + pen;
  }
}

// ---------------- bf16 MFMA grouped MoE GEMM (128x256 tile, BK=32 dbuf, grid-stride, counted vmcnt) ----------------
// Epilogue writes f16 slots (halves combine traffic). T5 setprio around compute phase.
__global__ __launch_bounds__(256, 2) void moe_gemm(
    const short* __restrict__ hln, const short* __restrict__ WeT,
    const float* __restrict__ be, const int* __restrict__ cnt,
    const int* __restrict__ bucket, const float* __restrict__ bucketP,
    const int* __restrict__ bucketS,
    _Float16* __restrict__ slot0, _Float16* __restrict__ slot1) {
  int e = blockIdx.z;
  int count = cnt[e];
  int n0 = blockIdx.y * 256;
  __shared__ short As[2][4096];   // [128][32] swizzled bf16
  __shared__ short Bs[2][8192];   // [256][32] swizzled bf16
  __shared__ int   toks[128];
  __shared__ float pws[128];
  __shared__ int   sls[128];
  int tid = threadIdx.x;
  int lane = tid & 63, w = tid >> 6;
  int wm = (w & 1) * 64, wn = (w >> 1) * 128;
  int l15 = lane & 15, quad = lane >> 4;
  const short* Bt = WeT + (size_t)e * 1048576;

  // A staging: 512 chunks (2/thread); B staging: 1024 chunks (4/thread).
  int PA0 = tid, PA1 = tid + 256;
  int cA0 = (PA0 & 3) ^ ((PA0 >> 3) & 3);
  int cA1 = (PA1 & 3) ^ ((PA1 >> 3) & 3);
  int PB[4]; size_t gB[4];
  #pragma unroll
  for (int j = 0; j < 4; j++) {
    PB[j] = tid + 256*j;
    int cb = (PB[j] & 3) ^ ((PB[j] >> 3) & 3);
    gB[j] = (size_t)(n0 + (PB[j] >> 2)) * 1024 + cb * 8;
  }

  for (int mtile = blockIdx.x; mtile * 128 < count; mtile += 16) {
    __syncthreads();   // guard toks/LDS reuse across mtile iterations
    if (tid < 128) {
      int idx = mtile*128 + tid;
      int ic = idx < count ? idx : count - 1;
      toks[tid] = bucket[e*8192 + ic];
      pws[tid]  = bucketP[e*8192 + ic];
      sls[tid]  = bucketS[e*8192 + ic];
    }
    __syncthreads();

    size_t gA0 = (size_t)toks[PA0 >> 2] * 1024 + cA0 * 8;
    size_t gA1 = (size_t)toks[PA1 >> 2] * 1024 + cA1 * 8;

    f32x4 acc[4][8] = {};

    // prologue: stage K-slice 0 into buffer 0 (6 loads/thread)
    gld16(hln + gA0, &As[0][PA0*8]);
    gld16(hln + gA1, &As[0][PA1*8]);
    #pragma unroll
    for (int j = 0; j < 4; j++) gld16(Bt + gB[j], &Bs[0][PB[j]*8]);

    int cur = 0;
    for (int it = 0; it < 32; ++it) {
      if (it < 31) {
        int kb = (it + 1) * 32;
        int nb = cur ^ 1;
        gld16(hln + gA0 + kb, &As[nb][PA0*8]);
        gld16(hln + gA1 + kb, &As[nb][PA1*8]);
        #pragma unroll
        for (int j = 0; j < 4; j++) gld16(Bt + gB[j] + kb, &Bs[nb][PB[j]*8]);
        asm volatile("s_waitcnt vmcnt(6)" ::: "memory");  // loads(it) done; loads(it+1) fly
      } else {
        asm volatile("s_waitcnt vmcnt(0)" ::: "memory");
      }
      __builtin_amdgcn_s_barrier();
      __builtin_amdgcn_sched_barrier(0);
      __builtin_amdgcn_s_setprio(1);
      bf16x8 bfr[8];
      #pragma unroll
      for (int nt = 0; nt < 8; nt++) {
        int row = wn + nt*16 + l15;
        int pc = quad ^ ((row >> 1) & 3);
        bfr[nt] = *(const bf16x8*)&Bs[cur][row*32 + pc*8];
      }
      #pragma unroll
      for (int mt = 0; mt < 4; mt++) {
        int row = wm + mt*16 + l15;
        int pc = quad ^ ((row >> 1) & 3);
        bf16x8 af = *(const bf16x8*)&As[cur][row*32 + pc*8];
        #pragma unroll
        for (int nt = 0; nt < 8; nt++)
          acc[mt][nt] = __builtin_amdgcn_mfma_f32_16x16x32_bf16(af, bfr[nt], acc[mt][nt], 0, 0, 0);
      }
      __builtin_amdgcn_s_setprio(0);
      asm volatile("s_waitcnt lgkmcnt(0)" ::: "memory");
      __builtin_amdgcn_sched_barrier(0);
      __builtin_amdgcn_s_barrier();
      cur ^= 1;
    }

    #pragma unroll
    for (int mt = 0; mt < 4; mt++) {
      #pragma unroll
      for (int r = 0; r < 4; r++) {
        int m = wm + mt*16 + quad*4 + r;
        if (mtile*128 + m < count) {
          int tok = toks[m];
          float pp = pws[m];
          _Float16* dst = sls[m] ? slot1 : slot0;
          #pragma unroll
          for (int nt = 0; nt < 8; nt++) {
            int col = n0 + wn + nt*16 + l15;
            dst[(size_t)tok*1024 + col] = (_Float16)(pp * (acc[mt][nt][r] + be[e*1024 + col]));
          }
        }
      }
    }
  }
}

// ---------------- final combine (f16 slots) ----------------
__global__ __launch_bounds__(256) void final_add(float* __restrict__ out,
    const _Float16* __restrict__ s0, const _Float16* __restrict__ s1) {
  const int total = 8388608 / 8;   // per 8 elements
  for (int i = blockIdx.x*256 + threadIdx.x; i < total; i += gridDim.x*256) {
    f16x8 a0 = ((const f16x8*)s0)[i];
    f16x8 a1 = ((const f16x8*)s1)[i];
    float4 o0 = ((float4*)out)[2*i];
    float4 o1 = ((float4*)out)[2*i + 1];
    o0.x += (float)a0[0] + (float)a1[0]; o0.y += (float)a0[1] + (float)a1[1];
    o0.z += (float)a0[2] + (float)a1[2]; o0.w += (float)a0[3] + (float)a1[3];
    o1.x += (float)a0[4] + (float)a1[4]; o1.y += (float)a0[5] + (float)a1[5];
    o1.z += (float)a0[6] + (float)a1[6]; o1.w += (float)a0[7] + (float)a1[7];
    ((float4*)out)[2*i] = o0;
    ((float4*)out)[2*i + 1] = o1;
  }
}

// ---------------- host launcher ----------------
extern "C" void kernel_launch(void* const* d_in, const int* in_sizes, int n_in,
                              void* d_out, int out_size, void* d_ws, size_t ws_size,
                              hipStream_t stream) {
  const float* x    = (const float*)d_in[0];
  const float* Wq   = (const float*)d_in[1];
  const float* bq   = (const float*)d_in[2];
  const float* Wk   = (const float*)d_in[3];
  const float* bk   = (const float*)d_in[4];
  const float* Wv   = (const float*)d_in[5];
  const float* bv   = (const float*)d_in[6];
  const float* Wo   = (const float*)d_in[7];
  const float* bo   = (const float*)d_in[8];
  const float* ln1g = (const float*)d_in[9];
  const float* ln1b = (const float*)d_in[10];
  const float* ln2g = (const float*)d_in[11];
  const float* ln2b = (const float*)d_in[12];
  const float* Wg   = (const float*)d_in[13];
  const float* bg   = (const float*)d_in[14];
  const float* We   = (const float*)d_in[15];
  const float* be   = (const float*)d_in[16];
  float* out = (float*)d_out;

  char* ws = (char*)d_ws;
  size_t off = 0;
  auto alloc = [&](size_t bytes) { char* p = ws + off; off += (bytes + 255) & ~(size_t)255; return p; };
  _Float16* xh  = (_Float16*)alloc(16777216);  // 8192x1024 f16 (LN1 hi); reused as Oh
  _Float16* xl  = (_Float16*)alloc(16777216);  // (LN1 lo*2048); reused as Ol
  float* Qs    = (float*)alloc(33554432);      // 8192x1024 f32; reused as hln
  float* Kf    = (float*)alloc(4194304);
  float* Vf    = (float*)alloc(4194304);
  short* WeT   = (short*)alloc(16777216);
  float* slot0 = (float*)alloc(33554432);      // f16 use: 16MB; front also WoT scratch
  float* slot1 = (float*)alloc(33554432);      // f16 use: 16MB; front also BTqkv scratch
  int*   bucket  = (int*)alloc(262144);
  float* bucketP = (float*)alloc(262144);
  int*   bucketS = (int*)alloc(262144);
  int*   cnt     = (int*)alloc(256);
  float* entArr  = (float*)alloc(32768);
  int*   e1e2    = (int*)alloc(32768);
  float2* p12    = (float2*)alloc(65536);
  _Float16* Oh = xh;            // alias: xh/xl dead after QKV GEMM
  _Float16* Ol = xl;
  short* hln   = (short*)Qs;    // alias: Qs dead after attention
  _Float16* WoTh    = (_Float16*)slot0;
  _Float16* WoTl    = (_Float16*)(slot0 + 524288);
  _Float16* BTqkv_h = (_Float16*)slot1;
  _Float16* BTqkv_l = (_Float16*)((char*)slot1 + 2621440);

  hipMemsetAsync(cnt, 0, 256, stream);
  prologue_fused<<<18688, 256, 0, stream>>>(x, ln1g, ln1b, Wq, Wk, Wv, Wo, We,
                                            xh, xl, BTqkv_h, BTqkv_l, WoTh, WoTl, WeT);
  gemm_dma<0><<<dim3(64,10), 256, 0, stream>>>(xh, xl, BTqkv_h, BTqkv_l, bq, bk, bv,
                                               nullptr, Qs, Kf, Vf);
  attn_mfma<<<dim3(4,16,32), 256, 0, stream>>>(Qs, Kf, Vf, Oh, Ol);
  gemm_dma<1><<<dim3(64,8), 256, 0, stream>>>(Oh, Ol, WoTh, WoTl, bo, nullptr, nullptr,
                                              x, out, nullptr, nullptr);
  ln2_gating<<<2048, 256, 0, stream>>>(out, ln2g, ln2b, Wg, bg, hln, e1e2, p12, entArr);
  scatter_kernel<<<64, 128, 0, stream>>>(e1e2, p12, cnt, bucket, bucketP, bucketS);
  aux_kernel<<<1, 256, 0, stream>>>(entArr, cnt, out + 8388608);
  moe_gemm<<<dim3(16,4,8), 256, 0, stream>>>(hln, WeT, be, cnt, bucket, bucketP, bucketS,
                                             (_Float16*)slot0, (_Float16*)slot1);
  final_add<<<2048, 256, 0, stream>>>(out, (const _Float16*)slot0, (const _Float16*)slot1);
}

// Round 16
// 476.153 us; speedup vs baseline: 1.1250x; 1.0451x over previous
//
#include <hip/hip_runtime.h>
#include <hip/hip_bf16.h>
#include <stdint.h>

// ---------------- types / helpers ----------------
typedef __attribute__((ext_vector_type(8))) short bf16x8;
typedef __attribute__((ext_vector_type(8))) _Float16 f16x8;
typedef __attribute__((ext_vector_type(4))) _Float16 f16x4;
typedef __attribute__((ext_vector_type(4))) float f32x4;

__device__ __forceinline__ short f2bf(float f) {
  __hip_bfloat16 h = __float2bfloat16(f);
  union { __hip_bfloat16 h; short s; } u; u.h = h; return u.s;
}

__device__ __forceinline__ unsigned pk2(float a, float b) {
  union { _Float16 h; unsigned short s; } ua, ub;
  ua.h = (_Float16)a; ub.h = (_Float16)b;
  return (unsigned)ua.s | ((unsigned)ub.s << 16);
}

// async global->LDS, 16B per lane. LDS dest must be wave-uniform base + lane*16.
__device__ __forceinline__ void gld16(const void* g, void* l) {
  __builtin_amdgcn_global_load_lds((const __attribute__((address_space(1))) void*)g,
                                   (__attribute__((address_space(3))) void*)l, 16, 0, 0);
}

__device__ __forceinline__ float wave_sum64(float v) {
  #pragma unroll
  for (int off = 1; off < 64; off <<= 1) v += __shfl_xor(v, off);
  return v;
}
__device__ __forceinline__ double wave_sum64d(double v) {
  #pragma unroll
  for (int off = 1; off < 64; off <<= 1) v += __shfl_xor(v, off);
  return v;
}

// ---------------- fused prologue: We transpose + 4 weight splits + LN1 ----------------
// Block map: [0,8192) transpose_We | [8192,10496) t_w_f16 {Wq,Wk,Wv,Wo} | [10496,18688) ln_split.
__global__ __launch_bounds__(256) void prologue_fused(
    const float* __restrict__ x, const float* __restrict__ ln1g, const float* __restrict__ ln1b,
    const float* __restrict__ Wq, const float* __restrict__ Wk,
    const float* __restrict__ Wv, const float* __restrict__ Wo,
    const float* __restrict__ We,
    _Float16* __restrict__ xh, _Float16* __restrict__ xl,
    _Float16* __restrict__ BTqkv_h, _Float16* __restrict__ BTqkv_l,
    _Float16* __restrict__ WoTh, _Float16* __restrict__ WoTl,
    short* __restrict__ WeT) {
  __shared__ float tile[32][33];
  __shared__ float pa[4], pb[4];
  int b = blockIdx.x;
  int tid = threadIdx.x;

  if (b < 8192) {
    // ---- transpose_We (fp32 -> bf16, per expert) ----
    int e = b >> 10, rem = b & 1023;
    int kt = rem & 31, nt = rem >> 5;
    int tx = tid & 31, ty = tid >> 5;
    const float* src = We + (size_t)e * 1048576;
    short* dst = WeT + (size_t)e * 1048576;
    #pragma unroll
    for (int i = 0; i < 4; i++)
      tile[ty + 8*i][tx] = src[(size_t)(kt*32 + ty + 8*i)*1024 + nt*32 + tx];
    __syncthreads();
    #pragma unroll
    for (int i = 0; i < 4; i++)
      dst[(size_t)(nt*32 + ty + 8*i)*1024 + kt*32 + tx] = f2bf(tile[tx][ty + 8*i]);
  } else if (b < 10496) {
    // ---- weight transpose + fp16 hi/lo split ----
    int bb = b - 8192;
    const float* src; int srcN, kt, nt, row0;
    _Float16 *dh, *dl;
    if (bb < 1024)      { src = Wq; srcN = 1024; kt = bb & 31; nt = bb >> 5; row0 = 0;    dh = BTqkv_h; dl = BTqkv_l; }
    else if (bb < 1152) { int c = bb - 1024; src = Wk; srcN = 128; kt = c & 31; nt = c >> 5; row0 = 1024; dh = BTqkv_h; dl = BTqkv_l; }
    else if (bb < 1280) { int c = bb - 1152; src = Wv; srcN = 128; kt = c & 31; nt = c >> 5; row0 = 1152; dh = BTqkv_h; dl = BTqkv_l; }
    else                { int c = bb - 1280; src = Wo; srcN = 1024; kt = c & 31; nt = c >> 5; row0 = 0;   dh = WoTh;    dl = WoTl; }
    int tx = tid & 31, ty = tid >> 5;
    #pragma unroll
    for (int i = 0; i < 4; i++)
      tile[ty + 8*i][tx] = src[(size_t)(kt*32 + ty + 8*i)*srcN + nt*32 + tx];
    __syncthreads();
    #pragma unroll
    for (int i = 0; i < 4; i++) {
      float v = tile[tx][ty + 8*i];
      _Float16 h = (_Float16)v;
      _Float16 l = (_Float16)((v - (float)h) * 2048.0f);
      size_t o = (size_t)(row0 + nt*32 + ty + 8*i)*1024 + kt*32 + tx;
      dh[o] = h; dl[o] = l;
    }
  } else {
    // ---- LN1: emits split-f16 (hi, lo*2048) ----
    int t = b - 10496;
    const float4 v = ((const float4*)(x + (size_t)t * 1024))[tid];
    float s = v.x + v.y + v.z + v.w;
    float s2 = v.x*v.x + v.y*v.y + v.z*v.z + v.w*v.w;
    s = wave_sum64(s); s2 = wave_sum64(s2);
    int wid = tid >> 6, lane = tid & 63;
    if (lane == 0) { pa[wid] = s; pb[wid] = s2; }
    __syncthreads();
    float S = pa[0]+pa[1]+pa[2]+pa[3], S2 = pb[0]+pb[1]+pb[2]+pb[3];
    float mu = S * (1.f/1024.f);
    float var = S2 * (1.f/1024.f) - mu*mu;
    float rs = rsqrtf(var + 1e-5f);
    const float4 gv = ((const float4*)ln1g)[tid];
    const float4 bv = ((const float4*)ln1b)[tid];
    float4 o;
    o.x = (v.x-mu)*rs*gv.x + bv.x; o.y = (v.y-mu)*rs*gv.y + bv.y;
    o.z = (v.z-mu)*rs*gv.z + bv.z; o.w = (v.w-mu)*rs*gv.w + bv.w;
    f16x4 hv, lv;
    hv.x = (_Float16)o.x; lv.x = (_Float16)((o.x - (float)hv.x)*2048.f);
    hv.y = (_Float16)o.y; lv.y = (_Float16)((o.y - (float)hv.y)*2048.f);
    hv.z = (_Float16)o.z; lv.z = (_Float16)((o.z - (float)hv.z)*2048.f);
    hv.w = (_Float16)o.w; lv.w = (_Float16)((o.w - (float)hv.w)*2048.f);
    *(f16x4*)&xh[(size_t)t*1024 + tid*4] = hv;
    *(f16x4*)&xl[(size_t)t*1024 + tid*4] = lv;
  }
}

// ---------------- split-fp16 DMA MFMA GEMM (128x128, BK=32, dbuf, counted-vmcnt) ----------------
// XCD model (r13): same-A-panel blocks spaced 64 (== 0 mod 8) -> same XCD L2; keep
// x = m-tile fastest. T4 counted vmcnt(8); T5 setprio; swizzle cp = c ^ ((row>>1)&3).
template<int MODE>
__global__ __launch_bounds__(256, 2) void gemm_dma(
    const _Float16* __restrict__ Agh, const _Float16* __restrict__ Agl,
    const _Float16* __restrict__ BTh, const _Float16* __restrict__ BTl,
    const float* __restrict__ b0, const float* __restrict__ b1, const float* __restrict__ b2,
    const float* __restrict__ resid,
    float* __restrict__ out0, float* __restrict__ out1, float* __restrict__ out2) {
  int m0 = blockIdx.x * 128;
  int y = blockIdx.y;
  int n0 = y * 128;
  float* dst; const float* biasp; int dcol0, ld;
  if (MODE == 0) {
    if (y < 8)      { dst = out0; biasp = b0 + y*128; dcol0 = y*128; ld = 1024; }
    else if (y == 8){ dst = out1; biasp = b1; dcol0 = 0; ld = 128; }
    else            { dst = out2; biasp = b2; dcol0 = 0; ld = 128; }
  } else            { dst = out0; biasp = b0 + y*128; dcol0 = y*128; ld = 1024; }

  __shared__ _Float16 AhS[2][4096];   // [128][32] swizzled
  __shared__ _Float16 AlS[2][4096];
  __shared__ _Float16 BhS[2][4096];   // [128][32] swizzled
  __shared__ _Float16 BlS[2][4096];
  int tid = threadIdx.x;
  int lane = tid & 63, w = tid >> 6;
  int wm = (w & 1) * 64, wn = (w >> 1) * 64;
  int l15 = lane & 15, quad = lane >> 4;

  // Staging geometry (fixed across K): 2 chunks/thread per array (512 chunks each).
  int P0 = tid, P1 = tid + 256;
  int c0 = (P0 & 3) ^ ((P0 >> 3) & 3);
  int c1 = (P1 & 3) ^ ((P1 >> 3) & 3);
  size_t gA0 = (size_t)(m0 + (P0 >> 2)) * 1024 + c0 * 8;
  size_t gA1 = (size_t)(m0 + (P1 >> 2)) * 1024 + c1 * 8;
  size_t gB0 = (size_t)(n0 + (P0 >> 2)) * 1024 + c0 * 8;
  size_t gB1 = (size_t)(n0 + (P1 >> 2)) * 1024 + c1 * 8;

  f32x4 accM[4][4] = {};
  f32x4 accC[4][4] = {};

  // prologue: stage K-tile 0 into buffer 0 (8 loads/thread)
  gld16(Agh + gA0, &AhS[0][P0*8]);
  gld16(Agh + gA1, &AhS[0][P1*8]);
  gld16(Agl + gA0, &AlS[0][P0*8]);
  gld16(Agl + gA1, &AlS[0][P1*8]);
  gld16(BTh + gB0, &BhS[0][P0*8]);
  gld16(BTh + gB1, &BhS[0][P1*8]);
  gld16(BTl + gB0, &BlS[0][P0*8]);
  gld16(BTl + gB1, &BlS[0][P1*8]);

  int cur = 0;
  for (int it = 0; it < 32; ++it) {
    if (it < 31) {
      int kb = (it + 1) * 32;
      int nb = cur ^ 1;
      gld16(Agh + gA0 + kb, &AhS[nb][P0*8]);
      gld16(Agh + gA1 + kb, &AhS[nb][P1*8]);
      gld16(Agl + gA0 + kb, &AlS[nb][P0*8]);
      gld16(Agl + gA1 + kb, &AlS[nb][P1*8]);
      gld16(BTh + gB0 + kb, &BhS[nb][P0*8]);
      gld16(BTh + gB1 + kb, &BhS[nb][P1*8]);
      gld16(BTl + gB0 + kb, &BlS[nb][P0*8]);
      gld16(BTl + gB1 + kb, &BlS[nb][P1*8]);
      asm volatile("s_waitcnt vmcnt(8)" ::: "memory");   // loads(it) done; loads(it+1) fly
    } else {
      asm volatile("s_waitcnt vmcnt(0)" ::: "memory");
    }
    __builtin_amdgcn_s_barrier();
    __builtin_amdgcn_sched_barrier(0);
    __builtin_amdgcn_s_setprio(1);
    f16x8 bh[4], bl[4];
    #pragma unroll
    for (int nt = 0; nt < 4; nt++) {
      int row = wn + nt*16 + l15;
      int pc = quad ^ ((row >> 1) & 3);
      bh[nt] = *(const f16x8*)&BhS[cur][row*32 + pc*8];
      bl[nt] = *(const f16x8*)&BlS[cur][row*32 + pc*8];
    }
    #pragma unroll
    for (int mt = 0; mt < 4; mt++) {
      int row = wm + mt*16 + l15;
      int pc = quad ^ ((row >> 1) & 3);
      f16x8 ah = *(const f16x8*)&AhS[cur][row*32 + pc*8];
      f16x8 al = *(const f16x8*)&AlS[cur][row*32 + pc*8];
      #pragma unroll
      for (int nt = 0; nt < 4; nt++) {
        accM[mt][nt] = __builtin_amdgcn_mfma_f32_16x16x32_f16(ah, bh[nt], accM[mt][nt], 0, 0, 0);
        accC[mt][nt] = __builtin_amdgcn_mfma_f32_16x16x32_f16(ah, bl[nt], accC[mt][nt], 0, 0, 0);
        accC[mt][nt] = __builtin_amdgcn_mfma_f32_16x16x32_f16(al, bh[nt], accC[mt][nt], 0, 0, 0);
      }
    }
    __builtin_amdgcn_s_setprio(0);
    asm volatile("s_waitcnt lgkmcnt(0)" ::: "memory");   // own ds_reads landed
    __builtin_amdgcn_sched_barrier(0);
    __builtin_amdgcn_s_barrier();                        // buf[cur] free for reuse
    cur ^= 1;
  }

  const float inv2048 = 1.0f / 2048.0f;
  #pragma unroll
  for (int mt = 0; mt < 4; mt++)
    #pragma unroll
    for (int r = 0; r < 4; r++) {
      int row = m0 + wm + mt*16 + quad*4 + r;
      #pragma unroll
      for (int nt = 0; nt < 4; nt++) {
        int c = wn + nt*16 + l15;
        float v = accM[mt][nt][r] + accC[mt][nt][r]*inv2048 + biasp[c];
        if (MODE == 1) v += resid[(size_t)row*1024 + dcol0 + c];
        dst[(size_t)row*ld + dcol0 + c] = v;
      }
    }
}

// ---------------- MFMA windowed attention ----------------
// Epilogue writes split-f16 (hi, lo*2048) for the Wo DMA GEMM.
__global__ __launch_bounds__(256, 2) void attn_mfma(
    const float* __restrict__ Qs, const float* __restrict__ Kf, const float* __restrict__ Vf,
    _Float16* __restrict__ Oh, _Float16* __restrict__ Ol) {
  int qb = blockIdx.x, n = blockIdx.y;
  int b = blockIdx.z >> 4, h = blockIdx.z & 15;
  int g = h & 1;
  int tid = threadIdx.x;
  int lane = tid & 63, w = tid >> 6;
  int l15 = lane & 15, quad = lane >> 4;

  __shared__ __align__(16) char smem[70912];
  _Float16* Vt = (_Float16*)smem;                 // [64][264]
  _Float16* Qh = (_Float16*)(smem + 33792);       // [64][72]
  _Float16* Ql = (_Float16*)(smem + 43008);
  _Float16* Kh = (_Float16*)(smem + 52224);
  _Float16* Kl = (_Float16*)(smem + 61440);
  _Float16* Pm = (_Float16*)(smem + 33792);       // alias over Q/K
  float*   linv = (float*)(smem + 70656);

  int qtok0 = b*4096 + n*128 + qb*64;
  int key0  = b*4096 + n*128;

  #pragma unroll
  for (int i = 0; i < 4; i++) {
    int idx = tid + 256*i;
    int row = idx >> 4, c4 = idx & 15;
    float4 v = *(const float4*)&Qs[(size_t)(qtok0+row)*1024 + h*64 + c4*4];
    f16x4 hv, lv;
    hv.x = (_Float16)v.x; lv.x = (_Float16)(v.x - (float)hv.x);
    hv.y = (_Float16)v.y; lv.y = (_Float16)(v.y - (float)hv.y);
    hv.z = (_Float16)v.z; lv.z = (_Float16)(v.z - (float)hv.z);
    hv.w = (_Float16)v.w; lv.w = (_Float16)(v.w - (float)hv.w);
    *(f16x4*)&Qh[row*72 + c4*4] = hv;
    *(f16x4*)&Ql[row*72 + c4*4] = lv;
  }
  {
    int kk = tid >> 4, dd = tid & 15;
    #pragma unroll
    for (int i = 0; i < 8; i++) {
      int p = i*16 + kk;
      float4 v0 = *(const float4*)&Vf[(size_t)(key0 + 2*p    )*128 + g*64 + dd*4];
      float4 v1 = *(const float4*)&Vf[(size_t)(key0 + 2*p + 1)*128 + g*64 + dd*4];
      *(unsigned*)&Vt[(dd*4+0)*264 + 2*p] = pk2(v0.x, v1.x);
      *(unsigned*)&Vt[(dd*4+1)*264 + 2*p] = pk2(v0.y, v1.y);
      *(unsigned*)&Vt[(dd*4+2)*264 + 2*p] = pk2(v0.z, v1.z);
      *(unsigned*)&Vt[(dd*4+3)*264 + 2*p] = pk2(v0.w, v1.w);
    }
  }
  __syncthreads();

  f16x8 qh[2], ql[2];
  {
    int qrow = (w*16 + l15)*72;
    qh[0] = *(const f16x8*)&Qh[qrow + quad*8];
    qh[1] = *(const f16x8*)&Qh[qrow + 32 + quad*8];
    ql[0] = *(const f16x8*)&Ql[qrow + quad*8];
    ql[1] = *(const f16x8*)&Ql[qrow + 32 + quad*8];
  }

  f32x4 S[16];
  #pragma unroll
  for (int t = 0; t < 16; t++) S[t] = (f32x4){0.f,0.f,0.f,0.f};

  for (int c = 0; c < 4; c++) {
    if (c) __syncthreads();
    #pragma unroll
    for (int i = 0; i < 4; i++) {
      int idx = tid + 256*i;
      int row = idx >> 4, c4 = idx & 15;
      float4 v = *(const float4*)&Kf[(size_t)(key0 + c*64 + row)*128 + g*64 + c4*4];
      f16x4 hv, lv;
      hv.x = (_Float16)v.x; lv.x = (_Float16)(v.x - (float)hv.x);
      hv.y = (_Float16)v.y; lv.y = (_Float16)(v.y - (float)hv.y);
      hv.z = (_Float16)v.z; lv.z = (_Float16)(v.z - (float)hv.z);
      hv.w = (_Float16)v.w; lv.w = (_Float16)(v.w - (float)hv.w);
      *(f16x4*)&Kh[row*72 + c4*4] = hv;
      *(f16x4*)&Kl[row*72 + c4*4] = lv;
    }
    __syncthreads();
    #pragma unroll
    for (int t = 0; t < 4; t++) {
      int krow = (t*16 + l15)*72;
      f16x8 kh0 = *(const f16x8*)&Kh[krow + quad*8];
      f16x8 kh1 = *(const f16x8*)&Kh[krow + 32 + quad*8];
      f16x8 kl0 = *(const f16x8*)&Kl[krow + quad*8];
      f16x8 kl1 = *(const f16x8*)&Kl[krow + 32 + quad*8];
      int ti = c*4 + t;
      S[ti] = __builtin_amdgcn_mfma_f32_16x16x32_f16(qh[0], kh0, S[ti], 0, 0, 0);
      S[ti] = __builtin_amdgcn_mfma_f32_16x16x32_f16(ql[0], kh0, S[ti], 0, 0, 0);
      S[ti] = __builtin_amdgcn_mfma_f32_16x16x32_f16(qh[0], kl0, S[ti], 0, 0, 0);
      S[ti] = __builtin_amdgcn_mfma_f32_16x16x32_f16(qh[1], kh1, S[ti], 0, 0, 0);
      S[ti] = __builtin_amdgcn_mfma_f32_16x16x32_f16(ql[1], kh1, S[ti], 0, 0, 0);
      S[ti] = __builtin_amdgcn_mfma_f32_16x16x32_f16(qh[1], kl1, S[ti], 0, 0, 0);
    }
  }

  float lrow[4];
  #pragma unroll
  for (int r = 0; r < 4; r++) {
    float mx = S[0][r];
    #pragma unroll
    for (int t = 1; t < 16; t++) mx = fmaxf(mx, S[t][r]);
    mx = fmaxf(mx, __shfl_xor(mx, 1)); mx = fmaxf(mx, __shfl_xor(mx, 2));
    mx = fmaxf(mx, __shfl_xor(mx, 4)); mx = fmaxf(mx, __shfl_xor(mx, 8));
    float sum = 0.f;
    #pragma unroll
    for (int t = 0; t < 16; t++) {
      float e = __expf((S[t][r] - mx) * 0.125f);
      S[t][r] = e; sum += e;
    }
    sum += __shfl_xor(sum, 1); sum += __shfl_xor(sum, 2);
    sum += __shfl_xor(sum, 4); sum += __shfl_xor(sum, 8);
    lrow[r] = sum;
  }
  if (l15 == 0) {
    #pragma unroll
    for (int r = 0; r < 4; r++) linv[w*16 + quad*4 + r] = 1.f / lrow[r];
  }
  __syncthreads();

  #pragma unroll
  for (int r = 0; r < 4; r++) {
    int q = w*16 + quad*4 + r;
    bool mine = (l15 & 1) ? (r >= 2) : (r < 2);
    #pragma unroll
    for (int t = 0; t < 16; t++) {
      float own = S[t][r];
      float oth = __shfl_xor(own, 1);
      if (mine) {
        float e0 = (l15 & 1) ? oth : own;
        float e1 = (l15 & 1) ? own : oth;
        *(unsigned*)&Pm[q*264 + t*16 + (l15 & ~1)] = pk2(e0, e1);
      }
    }
  }
  __syncthreads();

  f32x4 O[4];
  #pragma unroll
  for (int t = 0; t < 4; t++) O[t] = (f32x4){0.f,0.f,0.f,0.f};
  {
    int prow = (w*16 + l15)*264;
    #pragma unroll
    for (int ks = 0; ks < 8; ks++) {
      f16x8 pa = *(const f16x8*)&Pm[prow + ks*32 + quad*8];
      #pragma unroll
      for (int t = 0; t < 4; t++) {
        f16x8 vb = *(const f16x8*)&Vt[(t*16 + l15)*264 + ks*32 + quad*8];
        O[t] = __builtin_amdgcn_mfma_f32_16x16x32_f16(pa, vb, O[t], 0, 0, 0);
      }
    }
  }

  #pragma unroll
  for (int r = 0; r < 4; r++) {
    int qlocal = w*16 + quad*4 + r;
    float inv = linv[qlocal];
    int orow = b*4096 + n*256 + qb*64 + qlocal;
    #pragma unroll
    for (int t = 0; t < 4; t++) {
      float o = O[t][r] * inv;
      _Float16 oh = (_Float16)o;
      _Float16 ol = (_Float16)((o - (float)oh) * 2048.f);
      size_t oo = (size_t)orow*1024 + h*64 + t*16 + l15;
      Oh[oo] = oh; Ol[oo] = ol;
    }
  }
}

// ---------------- fused LN2 + gating: one pass over h ----------------
// Block 0 also zeroes cnt[] (read only by the NEXT kernel -> kernel-boundary visibility).
__global__ __launch_bounds__(256) void ln2_gating(
    const float* __restrict__ h,
    const float* __restrict__ g2, const float* __restrict__ b2,
    const float* __restrict__ Wg, const float* __restrict__ bg,
    short* __restrict__ hln,
    int* __restrict__ e1e2, float2* __restrict__ p12, float* __restrict__ entArr,
    int* __restrict__ cnt) {
  int tid = threadIdx.x, lane = tid & 63, wid = tid >> 6;
  if (blockIdx.x == 0 && tid < 8) cnt[tid] = 0;   // replaces hipMemsetAsync
  int tok = blockIdx.x*4 + wid;
  const float* row = h + (size_t)tok * 1024;
  float4 xv4[4];
  float s = 0.f, s2 = 0.f;
  #pragma unroll
  for (int q = 0; q < 4; q++) {
    float4 xv = ((const float4*)row)[lane*4 + q];
    xv4[q] = xv;
    s  += xv.x + xv.y + xv.z + xv.w;
    s2 += xv.x*xv.x + xv.y*xv.y + xv.z*xv.z + xv.w*xv.w;
  }
  s = wave_sum64(s); s2 = wave_sum64(s2);
  float mu = s * (1.f/1024.f);
  float var = s2 * (1.f/1024.f) - mu*mu;
  float rs = rsqrtf(var + 1e-5f);
  double mud = (double)mu, rsd = (double)rs;
  double acc[8] = {};
  short* hrow = hln + (size_t)tok * 1024;
  #pragma unroll
  for (int q = 0; q < 4; q++) {
    float4 xv = xv4[q];
    float4 gv = ((const float4*)g2)[lane*4 + q];
    float4 bv = ((const float4*)b2)[lane*4 + q];
    float xs[4] = {xv.x, xv.y, xv.z, xv.w};
    float gs[4] = {gv.x, gv.y, gv.z, gv.w};
    float bs[4] = {bv.x, bv.y, bv.z, bv.w};
    short os[4];
    #pragma unroll
    for (int j = 0; j < 4; j++) {
      int i = lane*16 + q*4 + j;
      os[j] = f2bf((xs[j] - mu) * rs * gs[j] + bs[j]);
      double xn = ((double)xs[j] - mud) * rsd * (double)gs[j] + (double)bs[j];
      const float4 w0 = *(const float4*)&Wg[(size_t)i*8];
      const float4 w1 = *(const float4*)&Wg[(size_t)i*8 + 4];
      acc[0] += xn*(double)w0.x; acc[1] += xn*(double)w0.y;
      acc[2] += xn*(double)w0.z; acc[3] += xn*(double)w0.w;
      acc[4] += xn*(double)w1.x; acc[5] += xn*(double)w1.y;
      acc[6] += xn*(double)w1.z; acc[7] += xn*(double)w1.w;
    }
    short4 o = make_short4(os[0], os[1], os[2], os[3]);
    ((short4*)hrow)[lane*4 + q] = o;
  }
  #pragma unroll
  for (int e = 0; e < 8; e++) acc[e] = wave_sum64d(acc[e]) + (double)bg[e];
  int e1 = 0;
  #pragma unroll
  for (int e = 1; e < 8; e++) if (acc[e] > acc[e1]) e1 = e;
  int e2 = (e1 == 0) ? 1 : 0;
  #pragma unroll
  for (int e = 0; e < 8; e++) if (e != e1 && acc[e] > acc[e2]) e2 = e;
  float lf[8];
  #pragma unroll
  for (int e = 0; e < 8; e++) lf[e] = (float)acc[e];
  float mx = lf[0];
  #pragma unroll
  for (int e = 1; e < 8; e++) mx = fmaxf(mx, lf[e]);
  float ex[8], Z = 0.f;
  #pragma unroll
  for (int e = 0; e < 8; e++) { ex[e] = __expf(lf[e] - mx); Z += ex[e]; }
  float invZ = 1.f / Z, ent = 0.f;
  float p[8];
  #pragma unroll
  for (int e = 0; e < 8; e++) { p[e] = ex[e]*invZ; ent -= p[e]*__logf(p[e] + 1e-8f); }
  if (lane == 0) {
    e1e2[tok] = e1 | (e2 << 8);
    p12[tok]  = make_float2(p[e1], p[e2]);
    entArr[tok] = ent;
  }
}

// ---------------- gating phase 2: LDS-aggregated scatter ----------------
__global__ __launch_bounds__(128) void scatter_kernel(
    const int* __restrict__ e1e2, const float2* __restrict__ p12,
    int* __restrict__ cnt, int* __restrict__ bucket, float* __restrict__ bucketP,
    int* __restrict__ bucketS) {
  __shared__ int lcnt[8], base[8];
  int tid = threadIdx.x;
  if (tid < 8) lcnt[tid] = 0;
  __syncthreads();
  int tok = blockIdx.x*128 + tid;
  int ee = e1e2[tok];
  int e1 = ee & 255, e2 = ee >> 8;
  float2 p = p12[tok];
  int o1 = atomicAdd(&lcnt[e1], 1);
  int o2 = atomicAdd(&lcnt[e2], 1);
  __syncthreads();
  if (tid < 8) base[tid] = atomicAdd(&cnt[tid], lcnt[tid]);
  __syncthreads();
  int i1 = base[e1] + o1;
  bucket[e1*8192 + i1] = tok; bucketP[e1*8192 + i1] = p.x; bucketS[e1*8192 + i1] = 0;
  int i2 = base[e2] + o2;
  bucket[e2*8192 + i2] = tok; bucketP[e2*8192 + i2] = p.y; bucketS[e2*8192 + i2] = 1;
}

// ---------------- bf16 MFMA grouped MoE GEMM (128x256 tile, BK=32 dbuf, grid-stride, counted vmcnt) ----------------
// Epilogue writes f16 slots (halves combine traffic). T5 setprio around compute phase.
__global__ __launch_bounds__(256, 2) void moe_gemm(
    const short* __restrict__ hln, const short* __restrict__ WeT,
    const float* __restrict__ be, const int* __restrict__ cnt,
    const int* __restrict__ bucket, const float* __restrict__ bucketP,
    const int* __restrict__ bucketS,
    _Float16* __restrict__ slot0, _Float16* __restrict__ slot1) {
  int e = blockIdx.z;
  int count = cnt[e];
  int n0 = blockIdx.y * 256;
  __shared__ short As[2][4096];   // [128][32] swizzled bf16
  __shared__ short Bs[2][8192];   // [256][32] swizzled bf16
  __shared__ int   toks[128];
  __shared__ float pws[128];
  __shared__ int   sls[128];
  int tid = threadIdx.x;
  int lane = tid & 63, w = tid >> 6;
  int wm = (w & 1) * 64, wn = (w >> 1) * 128;
  int l15 = lane & 15, quad = lane >> 4;
  const short* Bt = WeT + (size_t)e * 1048576;

  // A staging: 512 chunks (2/thread); B staging: 1024 chunks (4/thread).
  int PA0 = tid, PA1 = tid + 256;
  int cA0 = (PA0 & 3) ^ ((PA0 >> 3) & 3);
  int cA1 = (PA1 & 3) ^ ((PA1 >> 3) & 3);
  int PB[4]; size_t gB[4];
  #pragma unroll
  for (int j = 0; j < 4; j++) {
    PB[j] = tid + 256*j;
    int cb = (PB[j] & 3) ^ ((PB[j] >> 3) & 3);
    gB[j] = (size_t)(n0 + (PB[j] >> 2)) * 1024 + cb * 8;
  }

  for (int mtile = blockIdx.x; mtile * 128 < count; mtile += 16) {
    __syncthreads();   // guard toks/LDS reuse across mtile iterations
    if (tid < 128) {
      int idx = mtile*128 + tid;
      int ic = idx < count ? idx : count - 1;
      toks[tid] = bucket[e*8192 + ic];
      pws[tid]  = bucketP[e*8192 + ic];
      sls[tid]  = bucketS[e*8192 + ic];
    }
    __syncthreads();

    size_t gA0 = (size_t)toks[PA0 >> 2] * 1024 + cA0 * 8;
    size_t gA1 = (size_t)toks[PA1 >> 2] * 1024 + cA1 * 8;

    f32x4 acc[4][8] = {};

    // prologue: stage K-slice 0 into buffer 0 (6 loads/thread)
    gld16(hln + gA0, &As[0][PA0*8]);
    gld16(hln + gA1, &As[0][PA1*8]);
    #pragma unroll
    for (int j = 0; j < 4; j++) gld16(Bt + gB[j], &Bs[0][PB[j]*8]);

    int cur = 0;
    for (int it = 0; it < 32; ++it) {
      if (it < 31) {
        int kb = (it + 1) * 32;
        int nb = cur ^ 1;
        gld16(hln + gA0 + kb, &As[nb][PA0*8]);
        gld16(hln + gA1 + kb, &As[nb][PA1*8]);
        #pragma unroll
        for (int j = 0; j < 4; j++) gld16(Bt + gB[j] + kb, &Bs[nb][PB[j]*8]);
        asm volatile("s_waitcnt vmcnt(6)" ::: "memory");  // loads(it) done; loads(it+1) fly
      } else {
        asm volatile("s_waitcnt vmcnt(0)" ::: "memory");
      }
      __builtin_amdgcn_s_barrier();
      __builtin_amdgcn_sched_barrier(0);
      __builtin_amdgcn_s_setprio(1);
      bf16x8 bfr[8];
      #pragma unroll
      for (int nt = 0; nt < 8; nt++) {
        int row = wn + nt*16 + l15;
        int pc = quad ^ ((row >> 1) & 3);
        bfr[nt] = *(const bf16x8*)&Bs[cur][row*32 + pc*8];
      }
      #pragma unroll
      for (int mt = 0; mt < 4; mt++) {
        int row = wm + mt*16 + l15;
        int pc = quad ^ ((row >> 1) & 3);
        bf16x8 af = *(const bf16x8*)&As[cur][row*32 + pc*8];
        #pragma unroll
        for (int nt = 0; nt < 8; nt++)
          acc[mt][nt] = __builtin_amdgcn_mfma_f32_16x16x32_bf16(af, bfr[nt], acc[mt][nt], 0, 0, 0);
      }
      __builtin_amdgcn_s_setprio(0);
      asm volatile("s_waitcnt lgkmcnt(0)" ::: "memory");
      __builtin_amdgcn_sched_barrier(0);
      __builtin_amdgcn_s_barrier();
      cur ^= 1;
    }

    #pragma unroll
    for (int mt = 0; mt < 4; mt++) {
      #pragma unroll
      for (int r = 0; r < 4; r++) {
        int m = wm + mt*16 + quad*4 + r;
        if (mtile*128 + m < count) {
          int tok = toks[m];
          float pp = pws[m];
          _Float16* dst = sls[m] ? slot1 : slot0;
          #pragma unroll
          for (int nt = 0; nt < 8; nt++) {
            int col = n0 + wn + nt*16 + l15;
            dst[(size_t)tok*1024 + col] = (_Float16)(pp * (acc[mt][nt][r] + be[e*1024 + col]));
          }
        }
      }
    }
  }
}

// ---------------- final combine (f16 slots) + aux epilogue ----------------
// Block 0 additionally computes the aux loss (entArr/cnt finalized two launches
// earlier -> plain loads safe) -- removes the separate aux_kernel dispatch.
__global__ __launch_bounds__(256) void final_add(float* __restrict__ out,
    const _Float16* __restrict__ s0, const _Float16* __restrict__ s1,
    const float* __restrict__ entArr, const int* __restrict__ cnt,
    float* __restrict__ auxOut) {
  int tid = threadIdx.x;
  if (blockIdx.x == 0) {
    float s = 0.f;
    for (int i = tid; i < 8192; i += 256) s += entArr[i];
    s = wave_sum64(s);
    __shared__ float pa[4];
    if ((tid & 63) == 0) pa[tid >> 6] = s;
    __syncthreads();
    if (tid == 0) {
      float tot = pa[0]+pa[1]+pa[2]+pa[3];
      float entMean = tot / 8192.f;
      float pen = 0.f;
      for (int e = 0; e < 8; e++) {
        float usage = (float)cnt[e] / (8192.f + 1e-8f);
        pen += fmaxf(usage - 0.4f, 0.f);
      }
      auxOut[0] = 0.05f * entMean + pen;
    }
  }
  const int total = 8388608 / 8;   // per 8 elements
  for (int i = blockIdx.x*256 + tid; i < total; i += gridDim.x*256) {
    f16x8 a0 = ((const f16x8*)s0)[i];
    f16x8 a1 = ((const f16x8*)s1)[i];
    float4 o0 = ((float4*)out)[2*i];
    float4 o1 = ((float4*)out)[2*i + 1];
    o0.x += (float)a0[0] + (float)a1[0]; o0.y += (float)a0[1] + (float)a1[1];
    o0.z += (float)a0[2] + (float)a1[2]; o0.w += (float)a0[3] + (float)a1[3];
    o1.x += (float)a0[4] + (float)a1[4]; o1.y += (float)a0[5] + (float)a1[5];
    o1.z += (float)a0[6] + (float)a1[6]; o1.w += (float)a0[7] + (float)a1[7];
    ((float4*)out)[2*i] = o0;
    ((float4*)out)[2*i + 1] = o1;
  }
}

// ---------------- host launcher ----------------
extern "C" void kernel_launch(void* const* d_in, const int* in_sizes, int n_in,
                              void* d_out, int out_size, void* d_ws, size_t ws_size,
                              hipStream_t stream) {
  const float* x    = (const float*)d_in[0];
  const float* Wq   = (const float*)d_in[1];
  const float* bq   = (const float*)d_in[2];
  const float* Wk   = (const float*)d_in[3];
  const float* bk   = (const float*)d_in[4];
  const float* Wv   = (const float*)d_in[5];
  const float* bv   = (const float*)d_in[6];
  const float* Wo   = (const float*)d_in[7];
  const float* bo   = (const float*)d_in[8];
  const float* ln1g = (const float*)d_in[9];
  const float* ln1b = (const float*)d_in[10];
  const float* ln2g = (const float*)d_in[11];
  const float* ln2b = (const float*)d_in[12];
  const float* Wg   = (const float*)d_in[13];
  const float* bg   = (const float*)d_in[14];
  const float* We   = (const float*)d_in[15];
  const float* be   = (const float*)d_in[16];
  float* out = (float*)d_out;

  char* ws = (char*)d_ws;
  size_t off = 0;
  auto alloc = [&](size_t bytes) { char* p = ws + off; off += (bytes + 255) & ~(size_t)255; return p; };
  _Float16* xh  = (_Float16*)alloc(16777216);  // 8192x1024 f16 (LN1 hi); reused as Oh
  _Float16* xl  = (_Float16*)alloc(16777216);  // (LN1 lo*2048); reused as Ol
  float* Qs    = (float*)alloc(33554432);      // 8192x1024 f32; reused as hln
  float* Kf    = (float*)alloc(4194304);
  float* Vf    = (float*)alloc(4194304);
  short* WeT   = (short*)alloc(16777216);
  float* slot0 = (float*)alloc(33554432);      // f16 use: 16MB; front also WoT scratch
  float* slot1 = (float*)alloc(33554432);      // f16 use: 16MB; front also BTqkv scratch
  int*   bucket  = (int*)alloc(262144);
  float* bucketP = (float*)alloc(262144);
  int*   bucketS = (int*)alloc(262144);
  int*   cnt     = (int*)alloc(256);
  float* entArr  = (float*)alloc(32768);
  int*   e1e2    = (int*)alloc(32768);
  float2* p12    = (float2*)alloc(65536);
  _Float16* Oh = xh;            // alias: xh/xl dead after QKV GEMM
  _Float16* Ol = xl;
  short* hln   = (short*)Qs;    // alias: Qs dead after attention
  _Float16* WoTh    = (_Float16*)slot0;
  _Float16* WoTl    = (_Float16*)(slot0 + 524288);
  _Float16* BTqkv_h = (_Float16*)slot1;
  _Float16* BTqkv_l = (_Float16*)((char*)slot1 + 2621440);

  prologue_fused<<<18688, 256, 0, stream>>>(x, ln1g, ln1b, Wq, Wk, Wv, Wo, We,
                                            xh, xl, BTqkv_h, BTqkv_l, WoTh, WoTl, WeT);
  gemm_dma<0><<<dim3(64,10), 256, 0, stream>>>(xh, xl, BTqkv_h, BTqkv_l, bq, bk, bv,
                                               nullptr, Qs, Kf, Vf);
  attn_mfma<<<dim3(4,16,32), 256, 0, stream>>>(Qs, Kf, Vf, Oh, Ol);
  gemm_dma<1><<<dim3(64,8), 256, 0, stream>>>(Oh, Ol, WoTh, WoTl, bo, nullptr, nullptr,
                                              x, out, nullptr, nullptr);
  ln2_gating<<<2048, 256, 0, stream>>>(out, ln2g, ln2b, Wg, bg, hln, e1e2, p12, entArr, cnt);
  scatter_kernel<<<64, 128, 0, stream>>>(e1e2, p12, cnt, bucket, bucketP, bucketS);
  moe_gemm<<<dim3(16,4,8), 256, 0, stream>>>(hln, WeT, be, cnt, bucket, bucketP, bucketS,
                                             (_Float16*)slot0, (_Float16*)slot1);
  final_add<<<2048, 256, 0, stream>>>(out, (const _Float16*)slot0, (const _Float16*)slot1,
                                      entArr, cnt, out + 8388608);
}